// Round 6
// baseline (743.553 us; speedup 1.0000x reference)
//
#include <hip/hip_runtime.h>
#include <hip/hip_bf16.h>
#include <math.h>

// ---------------------------------------------------------------------------
// Types
// ---------------------------------------------------------------------------
typedef short v8s __attribute__((ext_vector_type(8)));   // 8 x bf16 bits (4 VGPR)
typedef short v4s __attribute__((ext_vector_type(4)));   // 8 B
typedef float v4f __attribute__((ext_vector_type(4)));   // MFMA accumulator

__device__ __forceinline__ unsigned short f2bf(float f) {
  union { float f; unsigned u; } a; a.f = f;
  unsigned u = a.u + 0x7fffu + ((a.u >> 16) & 1u);   // RNE
  return (unsigned short)(u >> 16);
}

// async global->LDS, 16 B per lane; LDS dest = wave-uniform base + lane*16
__device__ __forceinline__ void gld_lds16(const unsigned short* g, unsigned short* l) {
  __builtin_amdgcn_global_load_lds(
      (const __attribute__((address_space(1))) void*)g,
      (__attribute__((address_space(3))) void*)l,
      16, 0, 0);
}

#define VMCNT(n)  asm volatile("s_waitcnt vmcnt(" #n ")" ::: "memory")
#define LGKM(n)   asm volatile("s_waitcnt lgkmcnt(" #n ")" ::: "memory")

// ---------------------------------------------------------------------------
// fp32 -> bf16 (same layout), vectorized x4
// ---------------------------------------------------------------------------
__global__ void cvt_f32_bf16(const float* __restrict__ in,
                             unsigned short* __restrict__ out, int n4) {
  int i = blockIdx.x * blockDim.x + threadIdx.x;
  if (i >= n4) return;
  float4 v = reinterpret_cast<const float4*>(in)[i];
  ushort4 o;
  o.x = f2bf(v.x); o.y = f2bf(v.y); o.z = f2bf(v.z); o.w = f2bf(v.w);
  reinterpret_cast<ushort4*>(out)[i] = o;
}

// ---------------------------------------------------------------------------
// fp32 [K,N] -> bf16 [N,K] transpose-convert (weights). block (32,8)
// ---------------------------------------------------------------------------
__global__ void cvt_transpose(const float* __restrict__ in,
                              unsigned short* __restrict__ out, int K, int N) {
  __shared__ float t[32][33];
  int bx = blockIdx.x, by = blockIdx.y;
  int tx = threadIdx.x, ty = threadIdx.y;
#pragma unroll
  for (int i = 0; i < 4; i++) {
    int k = by * 32 + ty + i * 8;
    t[ty + i * 8][tx] = in[(size_t)k * N + bx * 32 + tx];
  }
  __syncthreads();
#pragma unroll
  for (int i = 0; i < 4; i++) {
    int n = bx * 32 + ty + i * 8;
    out[(size_t)n * K + by * 32 + tx] = f2bf(t[tx][ty + i * 8]);
  }
}

// ---------------------------------------------------------------------------
// bf16 [rows, rowstride] per-head block -> Vt[b][h][64][kvpad] (V transpose)
// grid (ceil(Skv/64), H, B), 256 threads. OOB kv rows -> zero.
// ---------------------------------------------------------------------------
__global__ __launch_bounds__(256)
void transpose_v(const unsigned short* __restrict__ V,
                 unsigned short* __restrict__ Vt,
                 int rowstride, int batch_rows, int Skv, int kvpad) {
  __shared__ __align__(16) unsigned short t[64][80];
  int ch = blockIdx.x, h = blockIdx.y, b = blockIdx.z;
  int tid = threadIdx.x;
  int sr = tid >> 2, sc = (tid & 3) * 16;
  int gr = ch * 64 + sr;
  v8s v0 = {}, v1 = {};
  if (gr < Skv) {
    const unsigned short* p = V + (size_t)(b * batch_rows + gr) * rowstride + h * 64 + sc;
    v0 = *(const v8s*)p; v1 = *(const v8s*)(p + 8);
  }
  *(v8s*)&t[sr][sc]     = v0;
  *(v8s*)&t[sr][sc + 8] = v1;
  __syncthreads();
  int d  = tid >> 2;
  int k0 = (tid & 3) * 16;
  unsigned short* o = Vt + ((size_t)(b * 16 + h) * 64 + d) * kvpad + ch * 64 + k0;
  v8s o0, o1;
#pragma unroll
  for (int e = 0; e < 8; e++) { o0[e] = t[k0 + e][d]; o1[e] = t[k0 + 8 + e][d]; }
  *(v8s*)o       = o0;
  *(v8s*)(o + 8) = o1;
}

// ---------------------------------------------------------------------------
// 256x256-tile bf16 GEMM, R6: free-run 2-barrier K-tile with counted-vmcnt
// cross-barrier staging.
//   C[M,N] = act(A[M,K] @ B[K,N] + bias) -> bf16.  A row-major, BT=B^T [N,K].
// 512 threads = 8 waves (2M x 4N), BK=64, per-wave C 128x64 = acc[8][4].
//
// Rationale (R2-R4 post-mortem): lockstep phase schedules serialize the LDS
// pipe (48 ds_read_b128/SIMD/K-tile ~576cyc) with the MFMA pipe (128 MFMA
// ~640cyc) -> 40% MfmaUtil regardless of phase order. Here each K-half is a
// single compiler-scheduled region (12 reads + 32 MFMA per wave): fine-grain
// lgkm waits let MFMA start after its first reads and overlap the rest, and
// the 2 waves/SIMD free-run within the half (m114 overlap). Counted vmcnt
// keeps next-tile staging in flight across barriers (no vmcnt(0) drain).
//
// LDS: l{A,B}[buf][khalf][256 rows x 32 cols] bf16 = 128 KiB. Row = 64 B.
// Swizzle (R2-proven 0 conflicts): stored 16B-chunk p of row r holds logical
// chunk p ^ ((r>>1)&3); pre-swizzled global source + swizzled ds_read.
//
// Tile U (c=U&1):
//   stage (U+1)k1 -> [c^1][1]     (WAR: last read tile U-1 half1, retired
//                                  before boundary BAR via LGKM(0))
//   HALF0: 12 reads [c][0] + 32 MFMA (free order); LGKM(0); BAR-mid
//   stage (U+2)k0 -> [c][0]       (WAR: half0 reads retired at BAR-mid)
//   HALF1: 12 reads [c][1] + 32 MFMA; LGKM(0); vmcnt; BAR-boundary
// vmcnt ledger (4 gld_lds per k-half unit, per wave): issue order per tile =
// (U+1)k1 then (U+2)k0 -> at boundary 8 outstanding; vmcnt(4) drains (U+1)k1,
// keeps (U+2)k0 in flight. Entry invariant: 4 outstanding = (U+1)k0.
// Prologue: k0(0),k1(0),k0(1) -> vmcnt(4). Tail (U+2>=NT): vmcnt(0).
// LGKM(0) before each barrier forces every wave's ds_reads to RETIRE before
// the barrier (closes the in-flight-read vs cross-wave-overwrite race that
// compiler MFMA sinking could otherwise open -- rule #18).
// Requires N%256==0, K%64==0, NT>=2.
// ---------------------------------------------------------------------------
template<bool RELU>
__global__ __launch_bounds__(512, 2)
void gemm256(const unsigned short* __restrict__ A,
             const unsigned short* __restrict__ BT,
             const float* __restrict__ bias,
             unsigned short* __restrict__ Cb,
             int M, int N, int K, int lda, int ldb) {
  __shared__ __align__(16) unsigned short lA[2][2][8192];   // [buf][khalf]
  __shared__ __align__(16) unsigned short lB[2][2][8192];
  int tid  = threadIdx.x;
  int lane = tid & 63;
  int wave = tid >> 6;          // 0..7
  int wrow = wave >> 2;         // 0..1 -> C rows wrow*128
  int wcol = wave & 3;          // 0..3 -> C cols wcol*64
  int quad = lane >> 4;
  int l15  = lane & 15;
  int m0 = blockIdx.y * 256;
  int n0 = blockIdx.x * 256;
  int NT = K >> 6;

  // staging: per gld_lds call a wave covers 16 rows (lane: row=+lane>>2,
  // stored chunk p=lane&3); pre-swizzled source chunk = p ^ ((row>>1)&3)
  int srow  = wave * 16 + (lane >> 2);           // 0..127 (call 0)
  int scol8 = ((lane & 3) ^ ((lane >> 3) & 3)) << 3;
  const unsigned short* gA0 = A  + (size_t)(m0 + srow) * lda + scol8;
  const unsigned short* gB0 = BT + (size_t)(n0 + srow) * ldb + scol8;

  auto stA = [&](int U, int kh) {                // one k-half unit: 2 calls
    unsigned short* d = &lA[U & 1][kh][wave * 512];
    const unsigned short* s = gA0 + (size_t)U * 64 + kh * 32;
    gld_lds16(s, d);
    gld_lds16(s + (size_t)128 * lda, d + 4096);
  };
  auto stB = [&](int U, int kh) {
    unsigned short* d = &lB[U & 1][kh][wave * 512];
    const unsigned short* s = gB0 + (size_t)U * 64 + kh * 32;
    gld_lds16(s, d);
    gld_lds16(s + (size_t)128 * ldb, d + 4096);
  };

  // ds_read: row = subtile*16 + l15, chunk = quad ^ ((row>>1)&3)
  int rsw  = (l15 >> 1) & 3;
  int cho  = (quad ^ rsw) << 3;
  int aOff = (wrow * 128 + l15) * 32 + cho;      // + m*512, m=0..7
  int bOff = (wcol * 64  + l15) * 32 + cho;      // + n*512, n=0..3

  const v4f vzero = {0.f, 0.f, 0.f, 0.f};
  v4f acc[8][4];
#pragma unroll
  for (int i = 0; i < 8; i++)
#pragma unroll
    for (int j = 0; j < 4; j++) acc[i][j] = vzero;

  // prologue: (0)k0, (0)k1, (1)k0 issued; drain tile 0, keep (1)k0 in flight
  stA(0, 0); stB(0, 0);
  stA(0, 1); stB(0, 1);
  if (NT > 1) { stA(1, 0); stB(1, 0); VMCNT(4); }
  else        { VMCNT(0); }
  __builtin_amdgcn_s_barrier();
  __builtin_amdgcn_sched_barrier(0);

  for (int U = 0; U < NT; ++U) {
    int c = U & 1;
    v8s aF[8], bFr[4];

    // stage next tile's k1 (earliest issue point; WAR-safe past boundary BAR)
    if (U + 1 < NT) { stA(U + 1, 1); stB(U + 1, 1); }

    // ===== HALF 0: free-run reads + MFMA on [c][0] =====
    {
      const unsigned short* pA = &lA[c][0][0];
      const unsigned short* pB = &lB[c][0][0];
#pragma unroll
      for (int m = 0; m < 8; m++) aF[m]  = *(const v8s*)&pA[aOff + m * 512];
#pragma unroll
      for (int n = 0; n < 4; n++) bFr[n] = *(const v8s*)&pB[bOff + n * 512];
#pragma unroll
      for (int m = 0; m < 8; m++)
#pragma unroll
        for (int n = 0; n < 4; n++)
          acc[m][n] = __builtin_amdgcn_mfma_f32_16x16x32_bf16(aF[m], bFr[n], acc[m][n], 0, 0, 0);
    }
    LGKM(0);                                  // all half0 ds_reads retired
    __builtin_amdgcn_sched_barrier(0);
    __builtin_amdgcn_s_barrier();             // mid: [c][0] free to overwrite

    if (U + 2 < NT) { stA(U + 2, 0); stB(U + 2, 0); }

    // ===== HALF 1: free-run reads + MFMA on [c][1] =====
    {
      const unsigned short* pA = &lA[c][1][0];
      const unsigned short* pB = &lB[c][1][0];
#pragma unroll
      for (int m = 0; m < 8; m++) aF[m]  = *(const v8s*)&pA[aOff + m * 512];
#pragma unroll
      for (int n = 0; n < 4; n++) bFr[n] = *(const v8s*)&pB[bOff + n * 512];
#pragma unroll
      for (int m = 0; m < 8; m++)
#pragma unroll
        for (int n = 0; n < 4; n++)
          acc[m][n] = __builtin_amdgcn_mfma_f32_16x16x32_bf16(aF[m], bFr[n], acc[m][n], 0, 0, 0);
    }
    LGKM(0);                                  // all half1 ds_reads retired
    __builtin_amdgcn_sched_barrier(0);
    // boundary: drain (U+1)k1 (+k0, already drained), keep (U+2)k0 in flight
    if (U + 2 < NT) { VMCNT(4); } else { VMCNT(0); }
    __builtin_amdgcn_s_barrier();
    __builtin_amdgcn_sched_barrier(0);
  }

  // epilogue: C/D layout col=lane&15, row=quad*4+reg
#pragma unroll
  for (int j = 0; j < 4; j++) {
    int col = n0 + wcol * 64 + j * 16 + l15;
    float bv = bias[col];
#pragma unroll
    for (int i = 0; i < 8; i++) {
      int rb = m0 + wrow * 128 + i * 16 + quad * 4;
#pragma unroll
      for (int r = 0; r < 4; r++) {
        int row = rb + r;
        if (row < M) {
          float v = acc[i][j][r] + bv;
          if (RELU) v = fmaxf(v, 0.f);
          Cb[(size_t)row * N + col] = f2bf(v);
        }
      }
    }
  }
}

// ---------------------------------------------------------------------------
// bf16 MFMA GEMM (128x128 2-barrier structure, proven 0 conflicts):
//   C[M,N] = act(A[M,K] @ B[K,N] + bias),  A row-major, BT=B^T [N,K].
// Kept for N=1024 GEMMs (256-tile grid would be CU-starved) and tiny M.
// bias2/bsplit: cols >= bsplit take bias2[col-bsplit] (merged-weight GEMMs).
// ---------------------------------------------------------------------------
template<bool RELU, bool OUTF, bool OUTB>
__global__ __launch_bounds__(256)
void gemm_bf16(const unsigned short* __restrict__ A,
               const unsigned short* __restrict__ BT,
               const float* __restrict__ bias,
               const float* __restrict__ bias2, int bsplit,
               float* __restrict__ Cf, float* __restrict__ Cf2,
               unsigned short* __restrict__ Cb,
               int M, int N, int Kred, int ld) {
  __shared__ __align__(16) unsigned short lA[128 * 64];   // 16 KB
  __shared__ __align__(16) unsigned short lB[128 * 64];
  int tid  = threadIdx.x;
  int lane = tid & 63;
  int wave = tid >> 6;
  int wr = (wave >> 1) * 64;
  int wc = (wave & 1) * 64;
  int quad = lane >> 4;
  int l15  = lane & 15;
  int m0 = blockIdx.y * 128;
  int n0 = blockIdx.x * 128;
  int z  = blockIdx.z;

  const unsigned short* Az = A  + (size_t)z * Kred;
  const unsigned short* Bz = BT + (size_t)z * Kred;
  float* Cfo = z ? Cf2 : Cf;
  const float* biasz = z ? nullptr : bias;

  int srow   = tid >> 3;                       // 0..31
  int schunk = (tid & 7) ^ (srow & 7);
  const unsigned short* gA = Az + (size_t)(m0 + srow) * ld + schunk * 8;
  const unsigned short* gB = Bz + (size_t)(n0 + srow) * ld + schunk * 8;
  unsigned short* ldsA = lA + wave * 512;
  unsigned short* ldsB = lB + wave * 512;
  const size_t rowblk = (size_t)32 * ld;

  const v4f vzero = {0.f, 0.f, 0.f, 0.f};
  v4f acc[4][4];
#pragma unroll
  for (int i = 0; i < 4; i++)
#pragma unroll
    for (int j = 0; j < 4; j++) acc[i][j] = vzero;

  for (int k0 = 0; k0 < Kred; k0 += 64) {
#pragma unroll
    for (int i = 0; i < 4; i++) {
      gld_lds16(gA + k0 + i * rowblk, ldsA + i * 2048);
      gld_lds16(gB + k0 + i * rowblk, ldsB + i * 2048);
    }
    __syncthreads();
#pragma unroll
    for (int s = 0; s < 2; s++) {
      v8s aF[4], bF[4];
#pragma unroll
      for (int i = 0; i < 4; i++)
        aF[i] = *(const v8s*)&lA[(wr + i * 16 + l15) * 64 + (((s * 4 + quad) ^ (l15 & 7)) * 8)];
#pragma unroll
      for (int j = 0; j < 4; j++)
        bF[j] = *(const v8s*)&lB[(wc + j * 16 + l15) * 64 + (((s * 4 + quad) ^ (l15 & 7)) * 8)];
#pragma unroll
      for (int i = 0; i < 4; i++)
#pragma unroll
        for (int j = 0; j < 4; j++)
          acc[i][j] = __builtin_amdgcn_mfma_f32_16x16x32_bf16(aF[i], bF[j], acc[i][j], 0, 0, 0);
    }
    __syncthreads();
  }

#pragma unroll
  for (int j = 0; j < 4; j++) {
    int col = n0 + wc + j * 16 + l15;
    float bv = 0.f;
    if (biasz) bv = (bias2 && col >= bsplit) ? bias2[col - bsplit] : biasz[col];
#pragma unroll
    for (int i = 0; i < 4; i++) {
#pragma unroll
      for (int r = 0; r < 4; r++) {
        int row = m0 + wr + i * 16 + quad * 4 + r;
        if (row < M) {
          float v = acc[i][j][r] + bv;
          if (RELU) v = fmaxf(v, 0.f);
          if (OUTF) Cfo[(size_t)row * N + col] = v;
          if (OUTB && !z) Cb[(size_t)row * N + col] = f2bf(v);
        }
      }
    }
  }
}

// ---------------------------------------------------------------------------
// Flash-style MFMA attention. grid (Sq/64, H, B), 256 threads = 4 waves.
// T14 async-stage split (R5, proven +18us): next-chunk K/V global->reg
// prefetch issued before current chunk's compute; raw s_barrier + targeted
// lgkm waits instead of __syncthreads so the prefetch survives the barrier.
// ---------------------------------------------------------------------------
__global__ __launch_bounds__(256)
void attn_kernel(const unsigned short* __restrict__ Q,
                 const unsigned short* __restrict__ K,
                 const unsigned short* __restrict__ Vt,
                 unsigned short* __restrict__ O,
                 int q_rowstride, int kv_rowstride, int o_rowstride,
                 int q_batch_rows, int kv_batch_rows, int Skv, int kvpad,
                 float scale) {
  __shared__ __align__(16) unsigned short lK[64][72];      // [kv][d]
  __shared__ __align__(16) unsigned short lV[64][72];      // [d][kv]
  __shared__ __align__(16) unsigned short lP[4][16][72];   // per-wave P (A-layout src)
  int tid  = threadIdx.x;
  int lane = tid & 63;
  int wave = tid >> 6;
  int quad = lane >> 4;
  int l15  = lane & 15;
  int qt = blockIdx.x, h = blockIdx.y, b = blockIdx.z;

  const unsigned short* Qb  = Q  + (size_t)b * q_batch_rows * q_rowstride + h * 64;
  const unsigned short* Kb  = K  + (size_t)b * kv_batch_rows * kv_rowstride + h * 64;
  const unsigned short* Vtb = Vt + ((size_t)(b * 16 + h) * 64) * kvpad;

  v8s qf0, qf1;
  {
    const unsigned short* qr = Qb + (size_t)(qt * 64 + wave * 16 + l15) * q_rowstride + quad * 8;
    qf0 = *(const v8s*)(qr);
    qf1 = *(const v8s*)(qr + 32);
  }

  const v4f vzero = {0.f, 0.f, 0.f, 0.f};
  v4f o_acc[4];
#pragma unroll
  for (int t = 0; t < 4; t++) o_acc[t] = vzero;
  float m_r[4], l_r[4];
#pragma unroll
  for (int r = 0; r < 4; r++) { m_r[r] = -1e30f; l_r[r] = 0.f; }

  int sr = tid >> 2;
  int sc = (tid & 3) * 16;
  int nch = (Skv + 63) >> 6;

  // T14 prologue: prefetch chunk 0 K/V into registers
  v8s kv0 = {}, kv1 = {}, vv0, vv1;
  if (sr < Skv) {
    const unsigned short* kp = Kb + (size_t)sr * kv_rowstride + sc;
    kv0 = *(const v8s*)kp;  kv1 = *(const v8s*)(kp + 8);
  }
  {
    const unsigned short* vp = Vtb + (size_t)sr * kvpad + sc;
    vv0 = *(const v8s*)vp;  vv1 = *(const v8s*)(vp + 8);
  }

  for (int ch = 0; ch < nch; ch++) {
    int base = ch * 64;
    __builtin_amdgcn_s_barrier();           // prev chunk's LDS reads consumed
    __builtin_amdgcn_sched_barrier(0);
    *(v8s*)&lK[sr][sc]     = kv0;
    *(v8s*)&lK[sr][sc + 8] = kv1;
    {  // lV row stride 72 shorts: 16B-unaligned for odd rows -> 8B stores
      v4s a0 = {vv0[0], vv0[1], vv0[2], vv0[3]};
      v4s a1 = {vv0[4], vv0[5], vv0[6], vv0[7]};
      v4s a2 = {vv1[0], vv1[1], vv1[2], vv1[3]};
      v4s a3 = {vv1[4], vv1[5], vv1[6], vv1[7]};
      *(v4s*)&lV[sr][sc]      = a0;
      *(v4s*)&lV[sr][sc + 4]  = a1;
      *(v4s*)&lV[sr][sc + 8]  = a2;
      *(v4s*)&lV[sr][sc + 12] = a3;
    }
    // issue next-chunk loads (latency hides under the compute below)
    v8s kn0 = {}, kn1 = {}, vn0 = {}, vn1 = {};
    if (ch + 1 < nch) {
      int gr2 = base + 64 + sr;
      if (gr2 < Skv) {
        const unsigned short* kp2 = Kb + (size_t)gr2 * kv_rowstride + sc;
        kn0 = *(const v8s*)kp2;  kn1 = *(const v8s*)(kp2 + 8);
      }
      const unsigned short* vp2 = Vtb + (size_t)sr * kvpad + base + 64 + sc;
      vn0 = *(const v8s*)vp2;  vn1 = *(const v8s*)(vp2 + 8);
    }
    LGKM(0);                                 // own ds_writes landed
    __builtin_amdgcn_s_barrier();            // all writes visible
    __builtin_amdgcn_sched_barrier(0);

    float s[4][4];
#pragma unroll
    for (int t = 0; t < 4; t++) {
      v8s kf0 = *(const v8s*)&lK[t * 16 + l15][quad * 8];
      v8s kf1 = *(const v8s*)&lK[t * 16 + l15][32 + quad * 8];
      v4f sacc = vzero;
      sacc = __builtin_amdgcn_mfma_f32_16x16x32_bf16(qf0, kf0, sacc, 0, 0, 0);
      sacc = __builtin_amdgcn_mfma_f32_16x16x32_bf16(qf1, kf1, sacc, 0, 0, 0);
      int kvpos = base + t * 16 + l15;
      bool ok = kvpos < Skv;
#pragma unroll
      for (int r = 0; r < 4; r++) s[t][r] = ok ? sacc[r] * scale : -1e30f;
    }

#pragma unroll
    for (int r = 0; r < 4; r++) {
      float mx = fmaxf(fmaxf(s[0][r], s[1][r]), fmaxf(s[2][r], s[3][r]));
#pragma unroll
      for (int d = 1; d < 16; d <<= 1) mx = fmaxf(mx, __shfl_xor(mx, d));
      float mnew = fmaxf(m_r[r], mx);
      float alpha = __expf(m_r[r] - mnew);
      float sm = 0.f;
#pragma unroll
      for (int t = 0; t < 4; t++) { s[t][r] = __expf(s[t][r] - mnew); sm += s[t][r]; }
#pragma unroll
      for (int d = 1; d < 16; d <<= 1) sm += __shfl_xor(sm, d);
      l_r[r] = l_r[r] * alpha + sm;
      m_r[r] = mnew;
#pragma unroll
      for (int t = 0; t < 4; t++) o_acc[t][r] *= alpha;
    }

#pragma unroll
    for (int t = 0; t < 4; t++)
#pragma unroll
      for (int r = 0; r < 4; r++)
        lP[wave][quad * 4 + r][t * 16 + l15] = f2bf(s[t][r]);
    v8s pf0 = *(const v8s*)&lP[wave][l15][quad * 8];
    v8s pf1 = *(const v8s*)&lP[wave][l15][32 + quad * 8];
#pragma unroll
    for (int t = 0; t < 4; t++) {
      v8s vf0 = *(const v8s*)&lV[t * 16 + l15][quad * 8];
      v8s vf1 = *(const v8s*)&lV[t * 16 + l15][32 + quad * 8];
      o_acc[t] = __builtin_amdgcn_mfma_f32_16x16x32_bf16(pf0, vf0, o_acc[t], 0, 0, 0);
      o_acc[t] = __builtin_amdgcn_mfma_f32_16x16x32_bf16(pf1, vf1, o_acc[t], 0, 0, 0);
    }

    kv0 = kn0; kv1 = kn1; vv0 = vn0; vv1 = vn1;
  }

  int orow0 = b * q_batch_rows + qt * 64 + wave * 16;
#pragma unroll
  for (int t = 0; t < 4; t++) {
#pragma unroll
    for (int r = 0; r < 4; r++) {
      float v = o_acc[t][r] / l_r[r];
      O[(size_t)(orow0 + quad * 4 + r) * o_rowstride + h * 64 + t * 16 + l15] = f2bf(v);
    }
  }
}

// ---------------------------------------------------------------------------
// Fused residual + LayerNorm over D=1024. 256 threads, 4 cols/thread.
// ---------------------------------------------------------------------------
__global__ __launch_bounds__(256)
void ln_kernel(const float* base, const float* __restrict__ delta,
               const float* __restrict__ delta2,
               const float* __restrict__ g, const float* __restrict__ bb,
               float* outf, unsigned short* __restrict__ outb) {
  __shared__ float red[8];
  int row = blockIdx.x;
  int tid = threadIdx.x;
  float4 vb = ((const float4*)(base  + (size_t)row * 1024))[tid];
  float4 vd = ((const float4*)(delta + (size_t)row * 1024))[tid];
  float v0 = vb.x + vd.x, v1 = vb.y + vd.y, v2 = vb.z + vd.z, v3 = vb.w + vd.w;
  if (delta2) {
    float4 v2d = ((const float4*)(delta2 + (size_t)row * 1024))[tid];
    v0 += v2d.x; v1 += v2d.y; v2 += v2d.z; v3 += v2d.w;
  }
  float s = v0 + v1 + v2 + v3;
  float q = v0 * v0 + v1 * v1 + v2 * v2 + v3 * v3;
#pragma unroll
  for (int d = 1; d < 64; d <<= 1) { s += __shfl_xor(s, d); q += __shfl_xor(q, d); }
  int wave = tid >> 6, lane = tid & 63;
  if (lane == 0) { red[wave] = s; red[4 + wave] = q; }
  __syncthreads();
  s = red[0] + red[1] + red[2] + red[3];
  q = red[4] + red[5] + red[6] + red[7];
  float mean = s * (1.f / 1024.f);
  float var  = q * (1.f / 1024.f) - mean * mean;
  float rstd = rsqrtf(var + 1e-5f);
  float4 gg  = ((const float4*)g)[tid];
  float4 bv  = ((const float4*)bb)[tid];
  float o0 = (v0 - mean) * rstd * gg.x + bv.x;
  float o1 = (v1 - mean) * rstd * gg.y + bv.y;
  float o2 = (v2 - mean) * rstd * gg.z + bv.z;
  float o3 = (v3 - mean) * rstd * gg.w + bv.w;
  if (outf) {
    float4 o; o.x = o0; o.y = o1; o.z = o2; o.w = o3;
    ((float4*)(outf + (size_t)row * 1024))[tid] = o;
  }
  if (outb) {
    ushort4 u; u.x = f2bf(o0); u.y = f2bf(o1); u.z = f2bf(o2); u.w = f2bf(o3);
    ((ushort4*)(outb + (size_t)row * 1024))[tid] = u;
  }
}

// ---------------------------------------------------------------------------
// Launch
// ---------------------------------------------------------------------------
extern "C" void kernel_launch(void* const* d_in, const int* in_sizes, int n_in,
                              void* d_out, int out_size, void* d_ws, size_t ws_size,
                              hipStream_t stream) {
  const float* x     = (const float*)d_in[0];
  const float* y     = (const float*)d_in[1];
  const float* w_qkv = (const float*)d_in[2];
  const float* b_qkv = (const float*)d_in[3];
  const float* w_so  = (const float*)d_in[4];
  const float* b_so  = (const float*)d_in[5];
  const float* w_q   = (const float*)d_in[6];
  const float* b_q   = (const float*)d_in[7];
  const float* w_k   = (const float*)d_in[8];
  const float* b_k   = (const float*)d_in[9];
  const float* w_v   = (const float*)d_in[10];
  const float* b_v   = (const float*)d_in[11];
  const float* w_co  = (const float*)d_in[12];
  const float* b_co  = (const float*)d_in[13];
  const float* w1    = (const float*)d_in[14];
  const float* b1    = (const float*)d_in[15];
  const float* w2    = (const float*)d_in[16];
  const float* b2    = (const float*)d_in[17];
  const float* w3    = (const float*)d_in[18];
  const float* b3    = (const float*)d_in[19];
  const float* ln_g  = (const float*)d_in[20];
  const float* ln_b  = (const float*)d_in[21];

  char* ws = (char*)d_ws;
  auto US = [&](size_t off) { return (unsigned short*)(ws + off); };
  auto FP = [&](size_t off) { return (float*)(ws + off); };

  constexpr size_t o_wqkv = 0;                                 // [3072,1024] bf16
  constexpr size_t o_wso  = o_wqkv + 3072ull * 1024 * 2;       // [1024,1024]
  constexpr size_t o_wq   = o_wso  + 1024ull * 1024 * 2;
  constexpr size_t o_wk   = o_wq   + 1024ull * 1024 * 2;       // [1024,768]
  constexpr size_t o_wv   = o_wk   + 1024ull * 768 * 2;        // adjacent to wk!
  constexpr size_t o_wco  = o_wv   + 1024ull * 768 * 2;
  constexpr size_t o_w1   = o_wco  + 1024ull * 1024 * 2;       // [4096,1024]
  constexpr size_t o_w2   = o_w1   + 4096ull * 1024 * 2;       // [4096,4096]
  constexpr size_t o_w3   = o_w2   + 4096ull * 4096 * 2;       // [1024,4096]
  constexpr size_t o_xf   = o_w3   + 1024ull * 4096 * 2;       // x fp32 [4096,1024]
  constexpr size_t o_xbf  = o_xf   + 4096ull * 1024 * 4;       // x bf16
  constexpr size_t o_ybf  = o_xbf  + 4096ull * 1024 * 2;       // y bf16 [308,768]
  constexpr size_t o_dlt  = o_ybf  + 308ull * 768 * 2;         // delta fp32 [4096,1024]
  constexpr size_t o_R1   = o_dlt  + 4096ull * 1024 * 4;       // qkv bf16 [4096,3072]
  constexpr size_t o_attn = o_R1   + 4096ull * 3072 * 2;       // attn out bf16 [4096,1024]
  constexpr size_t o_R2   = o_attn + 4096ull * 1024 * 2;       // h2 bf16 [4096,4096]
  constexpr size_t o_qc  = o_R1;
  constexpr size_t o_kc  = o_R1 + 4096ull * 1024 * 2;          // merged kc|vc [308,2048]
  constexpr size_t o_h1  = o_R1;
  constexpr size_t o_h2  = o_R2;
  constexpr size_t o_dlt2 = o_R1;
  constexpr size_t o_vtS = o_R2;
  constexpr size_t o_vtC = o_R2 + 4ull * 16 * 64 * 1024 * 2;

  dim3 tb(32, 8);
  cvt_transpose<<<dim3(96, 32),  tb, 0, stream>>>(w_qkv, US(o_wqkv), 1024, 3072);
  cvt_transpose<<<dim3(32, 32),  tb, 0, stream>>>(w_so,  US(o_wso),  1024, 1024);
  cvt_transpose<<<dim3(32, 32),  tb, 0, stream>>>(w_q,   US(o_wq),   1024, 1024);
  cvt_transpose<<<dim3(32, 24),  tb, 0, stream>>>(w_k,   US(o_wk),   768,  1024);
  cvt_transpose<<<dim3(32, 24),  tb, 0, stream>>>(w_v,   US(o_wv),   768,  1024);
  cvt_transpose<<<dim3(32, 32),  tb, 0, stream>>>(w_co,  US(o_wco),  1024, 1024);
  cvt_transpose<<<dim3(128, 32), tb, 0, stream>>>(w1,    US(o_w1),   1024, 4096);
  cvt_transpose<<<dim3(128, 128),tb, 0, stream>>>(w2,    US(o_w2),   4096, 4096);
  cvt_transpose<<<dim3(32, 128), tb, 0, stream>>>(w3,    US(o_w3),   4096, 1024);

  cvt_f32_bf16<<<4096, 256, 0, stream>>>(x, US(o_xbf), 4096 * 1024 / 4);
  cvt_f32_bf16<<<231, 256, 0, stream>>>(y, US(o_ybf), 4 * 77 * 768 / 4);

  // --- self attention ---
  gemm256<false><<<dim3(12, 16), 512, 0, stream>>>(            // free-run 256^2
      US(o_xbf), US(o_wqkv), b_qkv, US(o_R1), 4096, 3072, 1024, 1024, 1024);
  transpose_v<<<dim3(16, 16, 4), 256, 0, stream>>>(
      US(o_R1) + 2048, US(o_vtS), 3072, 1024, 1024, 1024);
  attn_kernel<<<dim3(16, 16, 4), 256, 0, stream>>>(
      US(o_R1), US(o_R1) + 1024, US(o_vtS), US(o_attn),
      3072, 3072, 1024, 1024, 1024, 1024, 1024, 0.125f);
  gemm_bf16<false, true, false><<<dim3(8, 32, 2), 256, 0, stream>>>(   // split-K
      US(o_attn), US(o_wso), b_so, nullptr, 0,
      FP(o_dlt), FP(o_dlt2), nullptr, 4096, 1024, 512, 1024);
  ln_kernel<<<4096, 256, 0, stream>>>(x, FP(o_dlt), FP(o_dlt2), ln_g, ln_b,
                                      FP(o_xf), US(o_xbf));

  // --- cross attention ---
  gemm_bf16<false, false, true><<<dim3(8, 32, 1), 256, 0, stream>>>(
      US(o_xbf), US(o_wq), b_q, nullptr, 0,
      nullptr, nullptr, US(o_qc), 4096, 1024, 1024, 1024);
  // merged K|V projection: wk and wv are adjacent in ws -> one GEMM, N=2048
  gemm_bf16<false, false, true><<<dim3(16, 3, 1), 256, 0, stream>>>(
      US(o_ybf), US(o_wk), b_k, b_v, 1024,
      nullptr, nullptr, US(o_kc), 308, 2048, 768, 768);
  transpose_v<<<dim3(2, 16, 4), 256, 0, stream>>>(
      US(o_kc) + 1024, US(o_vtC), 2048, 77, 77, 128);
  attn_kernel<<<dim3(16, 16, 4), 256, 0, stream>>>(
      US(o_qc), US(o_kc), US(o_vtC), US(o_attn),
      1024, 2048, 1024, 1024, 77, 77, 128, 0.125f);
  gemm_bf16<false, true, false><<<dim3(8, 32, 2), 256, 0, stream>>>(   // split-K
      US(o_attn), US(o_wco), b_co, nullptr, 0,
      FP(o_dlt), FP(o_dlt2), nullptr, 4096, 1024, 512, 1024);
  ln_kernel<<<4096, 256, 0, stream>>>(FP(o_xf), FP(o_dlt), FP(o_dlt2), ln_g, ln_b,
                                      FP(o_xf), US(o_xbf));

  // --- FFN ---
  gemm256<true><<<dim3(16, 16), 512, 0, stream>>>(             // free-run 256^2
      US(o_xbf), US(o_w1), b1, US(o_h1), 4096, 4096, 1024, 1024, 1024);
  gemm256<true><<<dim3(16, 16), 512, 0, stream>>>(             // free-run 256^2
      US(o_h1), US(o_w2), b2, US(o_h2), 4096, 4096, 4096, 4096, 4096);
  gemm_bf16<false, true, false><<<dim3(8, 32, 2), 256, 0, stream>>>(   // split-K
      US(o_h2), US(o_w3), b3, nullptr, 0,
      FP(o_dlt), FP(o_dlt2), nullptr, 4096, 1024, 2048, 4096);
  ln_kernel<<<4096, 256, 0, stream>>>(FP(o_xf), FP(o_dlt), FP(o_dlt2), ln_g, ln_b,
                                      (float*)d_out, nullptr);
}

// Round 7
// 742.392 us; speedup vs baseline: 1.0016x; 1.0016x over previous
//
#include <hip/hip_runtime.h>
#include <hip/hip_bf16.h>
#include <math.h>

// ---------------------------------------------------------------------------
// Types
// ---------------------------------------------------------------------------
typedef short v8s __attribute__((ext_vector_type(8)));   // 8 x bf16 bits (4 VGPR)
typedef short v4s __attribute__((ext_vector_type(4)));   // 8 B
typedef float v4f __attribute__((ext_vector_type(4)));   // MFMA accumulator

__device__ __forceinline__ unsigned short f2bf(float f) {
  union { float f; unsigned u; } a; a.f = f;
  unsigned u = a.u + 0x7fffu + ((a.u >> 16) & 1u);   // RNE
  return (unsigned short)(u >> 16);
}

// async global->LDS, 16 B per lane; LDS dest = wave-uniform base + lane*16
__device__ __forceinline__ void gld_lds16(const unsigned short* g, unsigned short* l) {
  __builtin_amdgcn_global_load_lds(
      (const __attribute__((address_space(1))) void*)g,
      (__attribute__((address_space(3))) void*)l,
      16, 0, 0);
}

#define VMCNT(n)  asm volatile("s_waitcnt vmcnt(" #n ")" ::: "memory")
#define LGKM(n)   asm volatile("s_waitcnt lgkmcnt(" #n ")" ::: "memory")

// ---------------------------------------------------------------------------
// fp32 -> bf16 (same layout), vectorized x4
// ---------------------------------------------------------------------------
__global__ void cvt_f32_bf16(const float* __restrict__ in,
                             unsigned short* __restrict__ out, int n4) {
  int i = blockIdx.x * blockDim.x + threadIdx.x;
  if (i >= n4) return;
  float4 v = reinterpret_cast<const float4*>(in)[i];
  ushort4 o;
  o.x = f2bf(v.x); o.y = f2bf(v.y); o.z = f2bf(v.z); o.w = f2bf(v.w);
  reinterpret_cast<ushort4*>(out)[i] = o;
}

// ---------------------------------------------------------------------------
// fp32 [K,N] -> bf16 [N,K] transpose-convert (weights). block (32,8)
// ---------------------------------------------------------------------------
__global__ void cvt_transpose(const float* __restrict__ in,
                              unsigned short* __restrict__ out, int K, int N) {
  __shared__ float t[32][33];
  int bx = blockIdx.x, by = blockIdx.y;
  int tx = threadIdx.x, ty = threadIdx.y;
#pragma unroll
  for (int i = 0; i < 4; i++) {
    int k = by * 32 + ty + i * 8;
    t[ty + i * 8][tx] = in[(size_t)k * N + bx * 32 + tx];
  }
  __syncthreads();
#pragma unroll
  for (int i = 0; i < 4; i++) {
    int n = bx * 32 + ty + i * 8;
    out[(size_t)n * K + by * 32 + tx] = f2bf(t[tx][ty + i * 8]);
  }
}

// ---------------------------------------------------------------------------
// bf16 [rows, rowstride] per-head block -> Vt[b][h][64][kvpad] (V transpose)
// grid (ceil(Skv/64), H, B), 256 threads. OOB kv rows -> zero.
// ---------------------------------------------------------------------------
__global__ __launch_bounds__(256)
void transpose_v(const unsigned short* __restrict__ V,
                 unsigned short* __restrict__ Vt,
                 int rowstride, int batch_rows, int Skv, int kvpad) {
  __shared__ __align__(16) unsigned short t[64][80];
  int ch = blockIdx.x, h = blockIdx.y, b = blockIdx.z;
  int tid = threadIdx.x;
  int sr = tid >> 2, sc = (tid & 3) * 16;
  int gr = ch * 64 + sr;
  v8s v0 = {}, v1 = {};
  if (gr < Skv) {
    const unsigned short* p = V + (size_t)(b * batch_rows + gr) * rowstride + h * 64 + sc;
    v0 = *(const v8s*)p; v1 = *(const v8s*)(p + 8);
  }
  *(v8s*)&t[sr][sc]     = v0;
  *(v8s*)&t[sr][sc + 8] = v1;
  __syncthreads();
  int d  = tid >> 2;
  int k0 = (tid & 3) * 16;
  unsigned short* o = Vt + ((size_t)(b * 16 + h) * 64 + d) * kvpad + ch * 64 + k0;
  v8s o0, o1;
#pragma unroll
  for (int e = 0; e < 8; e++) { o0[e] = t[k0 + e][d]; o1[e] = t[k0 + 8 + e][d]; }
  *(v8s*)o       = o0;
  *(v8s*)(o + 8) = o1;
}

// ---------------------------------------------------------------------------
// 256x256-tile bf16 GEMM -- m201-style 8-phase template (R4 variant, the best
// measured: ~941 TF / 39% MfmaUtil / 0 bank conflicts). R7 adds T1 XCD-aware
// block swizzle (bijective; requires gridDim.x*gridDim.y % 8 == 0) to cut the
// 2.3x A/B-panel overfetch from round-robin XCD placement.
// Schedule variants (2-barrier 8-phase, 4-phase reg-prefetch, free-run) all
// land 38-40% MfmaUtil -- declared done at this structure.
// ---------------------------------------------------------------------------
#define PH_MFMA(AFR, IB, JB)                                                   \
  _Pragma("unroll")                                                            \
  for (int m = 0; m < 4; m++) {                                                \
    _Pragma("unroll")                                                          \
    for (int n = 0; n < 2; n++) {                                              \
      acc[IB + m][JB + n] = __builtin_amdgcn_mfma_f32_16x16x32_bf16(           \
          AFR[m][0], bF[n][0], acc[IB + m][JB + n], 0, 0, 0);                  \
      acc[IB + m][JB + n] = __builtin_amdgcn_mfma_f32_16x16x32_bf16(           \
          AFR[m][1], bF[n][1], acc[IB + m][JB + n], 0, 0, 0);                  \
    }                                                                          \
  }

template<bool RELU>
__global__ __launch_bounds__(512, 2)
void gemm256(const unsigned short* __restrict__ A,
             const unsigned short* __restrict__ BT,
             const float* __restrict__ bias,
             unsigned short* __restrict__ Cb,
             int M, int N, int K, int lda, int ldb) {
  __shared__ __align__(16) unsigned short lA[2][2][8192];   // [buf][mhalf]
  __shared__ __align__(16) unsigned short lB[2][2][8192];   // [buf][nhalf]
  int tid  = threadIdx.x;
  int lane = tid & 63;
  int wave = tid >> 6;          // 0..7
  int wrow = wave >> 2;         // 0..1
  int wcol = wave & 3;          // 0..3
  int quad = lane >> 4;
  int l15  = lane & 15;

  // T1: XCD-aware swizzle. HW-consecutive blocks round-robin XCDs; remap so
  // each XCD owns a contiguous range of tile-rows (A-panel reuse in its L2).
  int nwg  = gridDim.x * gridDim.y;           // must be % 8 == 0
  int flat = blockIdx.y * gridDim.x + blockIdx.x;
  int q8   = nwg >> 3;
  int swz  = (flat & 7) * q8 + (flat >> 3);
  int m0 = (swz / gridDim.x) * 256;
  int n0 = (swz % gridDim.x) * 256;
  int NT = K >> 6;

  // ---- staging maps (per gld_lds call: wave w covers 8 LDS rows) ----
  int lrow = lane >> 3;                         // 0..7 row-in-wave-slice
  int swz8 = ((lane & 7) ^ lrow) << 3;          // source chunk (shorts)
  const unsigned short* gA0 = A + (size_t)(m0 + wave * 8 + lrow) * lda + swz8;
  int rr = wave * 8 + lrow;                     // 0..63
  int nbase = (rr >> 5) * 64 + (rr & 31);
  const unsigned short* gB0 = BT + (size_t)(n0 + nbase) * ldb + swz8;

  auto stageA = [&](int U, int h, int rlo) {    // 64 rows of half h
    unsigned short* d = &lA[U & 1][h][(rlo + wave * 8) * 64];
    gld_lds16(gA0 + (size_t)(h * 128 + rlo) * lda + (size_t)U * 64, d);
  };
  auto stageB = [&](int U, int hB, int q) {     // rows q*64.. of nh-half hB
    unsigned short* d = &lB[U & 1][hB][(q * 64 + wave * 8) * 64];
    gld_lds16(gB0 + (size_t)(q * 128 + hB * 32) * ldb + (size_t)U * 64, d);
  };

  // ---- ds_read swizzled chunk offsets (shorts) ----
  int ch0 = (quad ^ (l15 & 7)) << 3;            // ks=0
  int ch1 = ch0 ^ 32;                            // ks=1 (chunk^4)
  int wcol32 = wcol * 32;

  const v4f vzero = {0.f, 0.f, 0.f, 0.f};
  v4f acc[8][4];
#pragma unroll
  for (int i = 0; i < 8; i++)
#pragma unroll
    for (int j = 0; j < 4; j++) acc[i][j] = vzero;

  v8s aF0[4][2], aF1[4][2], bF[2][2];

  // ---- prologue: U1,U2,U3(0) | U4(0), U1,U2,U3(1) ----
  stageA(0, 0, 0);  stageA(0, 1, 0);      // U1(0)
  stageB(0, 0, 0);  stageB(0, 0, 1);      // U2(0)
  stageA(0, 0, 64); stageA(0, 1, 64);     // U3(0)
  stageB(0, 1, 0);  stageB(0, 1, 1);      // U4(0)
  if (NT > 1) {
    stageA(1, 0, 0);  stageA(1, 1, 0);    // U1(1)
    stageB(1, 0, 0);  stageB(1, 0, 1);    // U2(1)
    stageA(1, 0, 64); stageA(1, 1, 64);   // U3(1)
    VMCNT(8);
  } else {
    VMCNT(0);
  }
  __builtin_amdgcn_s_barrier();

  for (int U = 0; U < NT; ++U) {
    int c = U & 1;
    bool tail = (U + 3 >= NT);
    const unsigned short* pA  = &lA[c][wrow][0];
    const unsigned short* pB0 = &lB[c][0][0];
    const unsigned short* pB1 = &lB[c][1][0];

    // ===== ph0 (mh0, nh0): 12 reads =====
#pragma unroll
    for (int m = 0; m < 4; m++) {
      int ro = (m * 16 + l15) * 64;
      aF0[m][0] = *(const v8s*)&pA[ro + ch0];
      aF0[m][1] = *(const v8s*)&pA[ro + ch1];
    }
#pragma unroll
    for (int n = 0; n < 2; n++) {
      int ro = (wcol32 + n * 16 + l15) * 64;
      bF[n][0] = *(const v8s*)&pB0[ro + ch0];
      bF[n][1] = *(const v8s*)&pB0[ro + ch1];
    }
    if (U + 1 < NT) { stageB(U + 1, 1, 0); stageB(U + 1, 1, 1); }  // U4(U+1)
    LGKM(8);
    __builtin_amdgcn_s_barrier();
    LGKM(0);
    __builtin_amdgcn_sched_barrier(0);
    __builtin_amdgcn_s_setprio(1);
    PH_MFMA(aF0, 0, 0)
    __builtin_amdgcn_s_setprio(0);
    __builtin_amdgcn_s_barrier();

    // ===== ph1 (mh1, nh0): 8 reads =====
#pragma unroll
    for (int m = 0; m < 4; m++) {
      int ro = (64 * 64) + (m * 16 + l15) * 64;
      aF1[m][0] = *(const v8s*)&pA[ro + ch0];
      aF1[m][1] = *(const v8s*)&pA[ro + ch1];
    }
    if (U + 2 < NT) { stageA(U + 2, 0, 0); stageA(U + 2, 1, 0); }  // U1(U+2)
    __builtin_amdgcn_s_barrier();
    LGKM(0);
    __builtin_amdgcn_sched_barrier(0);
    __builtin_amdgcn_s_setprio(1);
    PH_MFMA(aF1, 4, 0)
    __builtin_amdgcn_s_setprio(0);
    if (tail) { VMCNT(0); } else { VMCNT(10); }    // drains U4(U) for ph2
    __builtin_amdgcn_s_barrier();

    // ===== ph2 (mh1, nh1): 4 reads =====
#pragma unroll
    for (int n = 0; n < 2; n++) {
      int ro = (wcol32 + n * 16 + l15) * 64;
      bF[n][0] = *(const v8s*)&pB1[ro + ch0];
      bF[n][1] = *(const v8s*)&pB1[ro + ch1];
    }
    if (U + 2 < NT) { stageB(U + 2, 0, 0); stageB(U + 2, 0, 1); }  // U2(U+2)
    __builtin_amdgcn_s_barrier();
    LGKM(0);
    __builtin_amdgcn_sched_barrier(0);
    __builtin_amdgcn_s_setprio(1);
    PH_MFMA(aF1, 4, 2)
    __builtin_amdgcn_s_setprio(0);
    __builtin_amdgcn_s_barrier();

    // ===== ph3 (mh0, nh1): 0 reads =====
    if (U + 2 < NT) { stageA(U + 2, 0, 64); stageA(U + 2, 1, 64); } // U3(U+2)
    __builtin_amdgcn_s_barrier();
    __builtin_amdgcn_s_setprio(1);
    PH_MFMA(aF0, 0, 2)
    __builtin_amdgcn_s_setprio(0);
    if (tail) { VMCNT(0); } else { VMCNT(8); }     // drains U1-U3(U+1)
    __builtin_amdgcn_s_barrier();
  }

  // epilogue: C/D col=lane&15, row=quad*4+reg; i=mh*4+m, j=nh*2+n
#pragma unroll
  for (int j = 0; j < 4; j++) {
    int col = n0 + wcol * 64 + (j >> 1) * 32 + (j & 1) * 16 + l15;
    float bv = bias[col];
#pragma unroll
    for (int i = 0; i < 8; i++) {
      int rb = m0 + wrow * 128 + (i >> 2) * 64 + (i & 3) * 16 + quad * 4;
#pragma unroll
      for (int r = 0; r < 4; r++) {
        int row = rb + r;
        if (row < M) {
          float v = acc[i][j][r] + bv;
          if (RELU) v = fmaxf(v, 0.f);
          Cb[(size_t)row * N + col] = f2bf(v);
        }
      }
    }
  }
}

// ---------------------------------------------------------------------------
// bf16 MFMA GEMM (128x128 2-barrier structure, proven 0 conflicts):
//   C[M,N] = act(A[M,K] @ B[K,N] + bias),  A row-major, BT=B^T [N,K].
// Kept for N=1024 GEMMs (256-tile grid would be CU-starved) and tiny M.
// bias2/bsplit: cols >= bsplit take bias2[col-bsplit] (merged-weight GEMMs).
// ---------------------------------------------------------------------------
template<bool RELU, bool OUTF, bool OUTB>
__global__ __launch_bounds__(256)
void gemm_bf16(const unsigned short* __restrict__ A,
               const unsigned short* __restrict__ BT,
               const float* __restrict__ bias,
               const float* __restrict__ bias2, int bsplit,
               float* __restrict__ Cf, float* __restrict__ Cf2,
               unsigned short* __restrict__ Cb,
               int M, int N, int Kred, int ld) {
  __shared__ __align__(16) unsigned short lA[128 * 64];   // 16 KB
  __shared__ __align__(16) unsigned short lB[128 * 64];
  int tid  = threadIdx.x;
  int lane = tid & 63;
  int wave = tid >> 6;
  int wr = (wave >> 1) * 64;
  int wc = (wave & 1) * 64;
  int quad = lane >> 4;
  int l15  = lane & 15;
  int m0 = blockIdx.y * 128;
  int n0 = blockIdx.x * 128;
  int z  = blockIdx.z;

  const unsigned short* Az = A  + (size_t)z * Kred;
  const unsigned short* Bz = BT + (size_t)z * Kred;
  float* Cfo = z ? Cf2 : Cf;
  const float* biasz = z ? nullptr : bias;

  int srow   = tid >> 3;                       // 0..31
  int schunk = (tid & 7) ^ (srow & 7);
  const unsigned short* gA = Az + (size_t)(m0 + srow) * ld + schunk * 8;
  const unsigned short* gB = Bz + (size_t)(n0 + srow) * ld + schunk * 8;
  unsigned short* ldsA = lA + wave * 512;
  unsigned short* ldsB = lB + wave * 512;
  const size_t rowblk = (size_t)32 * ld;

  const v4f vzero = {0.f, 0.f, 0.f, 0.f};
  v4f acc[4][4];
#pragma unroll
  for (int i = 0; i < 4; i++)
#pragma unroll
    for (int j = 0; j < 4; j++) acc[i][j] = vzero;

  for (int k0 = 0; k0 < Kred; k0 += 64) {
#pragma unroll
    for (int i = 0; i < 4; i++) {
      gld_lds16(gA + k0 + i * rowblk, ldsA + i * 2048);
      gld_lds16(gB + k0 + i * rowblk, ldsB + i * 2048);
    }
    __syncthreads();
#pragma unroll
    for (int s = 0; s < 2; s++) {
      v8s aF[4], bF[4];
#pragma unroll
      for (int i = 0; i < 4; i++)
        aF[i] = *(const v8s*)&lA[(wr + i * 16 + l15) * 64 + (((s * 4 + quad) ^ (l15 & 7)) * 8)];
#pragma unroll
      for (int j = 0; j < 4; j++)
        bF[j] = *(const v8s*)&lB[(wc + j * 16 + l15) * 64 + (((s * 4 + quad) ^ (l15 & 7)) * 8)];
#pragma unroll
      for (int i = 0; i < 4; i++)
#pragma unroll
        for (int j = 0; j < 4; j++)
          acc[i][j] = __builtin_amdgcn_mfma_f32_16x16x32_bf16(aF[i], bF[j], acc[i][j], 0, 0, 0);
    }
    __syncthreads();
  }

#pragma unroll
  for (int j = 0; j < 4; j++) {
    int col = n0 + wc + j * 16 + l15;
    float bv = 0.f;
    if (biasz) bv = (bias2 && col >= bsplit) ? bias2[col - bsplit] : biasz[col];
#pragma unroll
    for (int i = 0; i < 4; i++) {
#pragma unroll
      for (int r = 0; r < 4; r++) {
        int row = m0 + wr + i * 16 + quad * 4 + r;
        if (row < M) {
          float v = acc[i][j][r] + bv;
          if (RELU) v = fmaxf(v, 0.f);
          if (OUTF) Cfo[(size_t)row * N + col] = v;
          if (OUTB && !z) Cb[(size_t)row * N + col] = f2bf(v);
        }
      }
    }
  }
}

// ---------------------------------------------------------------------------
// Flash-style MFMA attention. grid (Sq/64, H, B), 256 threads = 4 waves.
// T14 async-stage split (R5, proven +18us). R7 adds:
//  - T5 setprio around MFMA clusters (m191: +4-7% in this regime -- many
//    independent blocks/CU, waves at different phases).
//  - T13 defer-max THR=8: skip the rescale block (4 exp + 16 mul) when
//    __any(mx > m+8) is false (wave-uniform branch). First chunk always
//    rescales (m=-1e30); P bounded by e^8, f32 accum safe.
// ---------------------------------------------------------------------------
__global__ __launch_bounds__(256)
void attn_kernel(const unsigned short* __restrict__ Q,
                 const unsigned short* __restrict__ K,
                 const unsigned short* __restrict__ Vt,
                 unsigned short* __restrict__ O,
                 int q_rowstride, int kv_rowstride, int o_rowstride,
                 int q_batch_rows, int kv_batch_rows, int Skv, int kvpad,
                 float scale) {
  __shared__ __align__(16) unsigned short lK[64][72];      // [kv][d]
  __shared__ __align__(16) unsigned short lV[64][72];      // [d][kv]
  __shared__ __align__(16) unsigned short lP[4][16][72];   // per-wave P (A-layout src)
  int tid  = threadIdx.x;
  int lane = tid & 63;
  int wave = tid >> 6;
  int quad = lane >> 4;
  int l15  = lane & 15;
  int qt = blockIdx.x, h = blockIdx.y, b = blockIdx.z;

  const unsigned short* Qb  = Q  + (size_t)b * q_batch_rows * q_rowstride + h * 64;
  const unsigned short* Kb  = K  + (size_t)b * kv_batch_rows * kv_rowstride + h * 64;
  const unsigned short* Vtb = Vt + ((size_t)(b * 16 + h) * 64) * kvpad;

  v8s qf0, qf1;
  {
    const unsigned short* qr = Qb + (size_t)(qt * 64 + wave * 16 + l15) * q_rowstride + quad * 8;
    qf0 = *(const v8s*)(qr);
    qf1 = *(const v8s*)(qr + 32);
  }

  const v4f vzero = {0.f, 0.f, 0.f, 0.f};
  v4f o_acc[4];
#pragma unroll
  for (int t = 0; t < 4; t++) o_acc[t] = vzero;
  float m_r[4], l_r[4];
#pragma unroll
  for (int r = 0; r < 4; r++) { m_r[r] = -1e30f; l_r[r] = 0.f; }

  int sr = tid >> 2;
  int sc = (tid & 3) * 16;
  int nch = (Skv + 63) >> 6;

  // T14 prologue: prefetch chunk 0 K/V into registers
  v8s kv0 = {}, kv1 = {}, vv0, vv1;
  if (sr < Skv) {
    const unsigned short* kp = Kb + (size_t)sr * kv_rowstride + sc;
    kv0 = *(const v8s*)kp;  kv1 = *(const v8s*)(kp + 8);
  }
  {
    const unsigned short* vp = Vtb + (size_t)sr * kvpad + sc;
    vv0 = *(const v8s*)vp;  vv1 = *(const v8s*)(vp + 8);
  }

  for (int ch = 0; ch < nch; ch++) {
    int base = ch * 64;
    __builtin_amdgcn_s_barrier();           // prev chunk's LDS reads consumed
    __builtin_amdgcn_sched_barrier(0);
    *(v8s*)&lK[sr][sc]     = kv0;
    *(v8s*)&lK[sr][sc + 8] = kv1;
    {  // lV row stride 72 shorts: 16B-unaligned for odd rows -> 8B stores
      v4s a0 = {vv0[0], vv0[1], vv0[2], vv0[3]};
      v4s a1 = {vv0[4], vv0[5], vv0[6], vv0[7]};
      v4s a2 = {vv1[0], vv1[1], vv1[2], vv1[3]};
      v4s a3 = {vv1[4], vv1[5], vv1[6], vv1[7]};
      *(v4s*)&lV[sr][sc]      = a0;
      *(v4s*)&lV[sr][sc + 4]  = a1;
      *(v4s*)&lV[sr][sc + 8]  = a2;
      *(v4s*)&lV[sr][sc + 12] = a3;
    }
    // issue next-chunk loads (latency hides under the compute below)
    v8s kn0 = {}, kn1 = {}, vn0 = {}, vn1 = {};
    if (ch + 1 < nch) {
      int gr2 = base + 64 + sr;
      if (gr2 < Skv) {
        const unsigned short* kp2 = Kb + (size_t)gr2 * kv_rowstride + sc;
        kn0 = *(const v8s*)kp2;  kn1 = *(const v8s*)(kp2 + 8);
      }
      const unsigned short* vp2 = Vtb + (size_t)sr * kvpad + base + 64 + sc;
      vn0 = *(const v8s*)vp2;  vn1 = *(const v8s*)(vp2 + 8);
    }
    LGKM(0);                                 // own ds_writes landed
    __builtin_amdgcn_s_barrier();            // all writes visible
    __builtin_amdgcn_sched_barrier(0);

    float s[4][4];
    __builtin_amdgcn_s_setprio(1);
#pragma unroll
    for (int t = 0; t < 4; t++) {
      v8s kf0 = *(const v8s*)&lK[t * 16 + l15][quad * 8];
      v8s kf1 = *(const v8s*)&lK[t * 16 + l15][32 + quad * 8];
      v4f sacc = vzero;
      sacc = __builtin_amdgcn_mfma_f32_16x16x32_bf16(qf0, kf0, sacc, 0, 0, 0);
      sacc = __builtin_amdgcn_mfma_f32_16x16x32_bf16(qf1, kf1, sacc, 0, 0, 0);
      int kvpos = base + t * 16 + l15;
      bool ok = kvpos < Skv;
#pragma unroll
      for (int r = 0; r < 4; r++) s[t][r] = ok ? sacc[r] * scale : -1e30f;
    }
    __builtin_amdgcn_s_setprio(0);

    // row maxima (quad-uniform after reduce)
    float mxv[4];
#pragma unroll
    for (int r = 0; r < 4; r++) {
      float mx = fmaxf(fmaxf(s[0][r], s[1][r]), fmaxf(s[2][r], s[3][r]));
#pragma unroll
      for (int d = 1; d < 16; d <<= 1) mx = fmaxf(mx, __shfl_xor(mx, d));
      mxv[r] = mx;
    }
    // T13 defer-max: rescale only if some row grew past m + 8
    bool need = false;
#pragma unroll
    for (int r = 0; r < 4; r++) need = need || (mxv[r] > m_r[r] + 8.f);
    if (__any(need)) {
#pragma unroll
      for (int r = 0; r < 4; r++) {
        float mnew = fmaxf(m_r[r], mxv[r]);
        float alpha = __expf(m_r[r] - mnew);
        l_r[r] *= alpha;
        m_r[r] = mnew;
#pragma unroll
        for (int t = 0; t < 4; t++) o_acc[t][r] *= alpha;
      }
    }
    // P = exp(s - m), row-sum
#pragma unroll
    for (int r = 0; r < 4; r++) {
      float sm = 0.f;
#pragma unroll
      for (int t = 0; t < 4; t++) { s[t][r] = __expf(s[t][r] - m_r[r]); sm += s[t][r]; }
#pragma unroll
      for (int d = 1; d < 16; d <<= 1) sm += __shfl_xor(sm, d);
      l_r[r] += sm;
    }

#pragma unroll
    for (int t = 0; t < 4; t++)
#pragma unroll
      for (int r = 0; r < 4; r++)
        lP[wave][quad * 4 + r][t * 16 + l15] = f2bf(s[t][r]);
    v8s pf0 = *(const v8s*)&lP[wave][l15][quad * 8];
    v8s pf1 = *(const v8s*)&lP[wave][l15][32 + quad * 8];
    __builtin_amdgcn_s_setprio(1);
#pragma unroll
    for (int t = 0; t < 4; t++) {
      v8s vf0 = *(const v8s*)&lV[t * 16 + l15][quad * 8];
      v8s vf1 = *(const v8s*)&lV[t * 16 + l15][32 + quad * 8];
      o_acc[t] = __builtin_amdgcn_mfma_f32_16x16x32_bf16(pf0, vf0, o_acc[t], 0, 0, 0);
      o_acc[t] = __builtin_amdgcn_mfma_f32_16x16x32_bf16(pf1, vf1, o_acc[t], 0, 0, 0);
    }
    __builtin_amdgcn_s_setprio(0);

    kv0 = kn0; kv1 = kn1; vv0 = vn0; vv1 = vn1;
  }

  int orow0 = b * q_batch_rows + qt * 64 + wave * 16;
#pragma unroll
  for (int t = 0; t < 4; t++) {
#pragma unroll
    for (int r = 0; r < 4; r++) {
      float v = o_acc[t][r] / l_r[r];
      O[(size_t)(orow0 + quad * 4 + r) * o_rowstride + h * 64 + t * 16 + l15] = f2bf(v);
    }
  }
}

// ---------------------------------------------------------------------------
// Fused residual + LayerNorm over D=1024. 256 threads, 4 cols/thread.
// ---------------------------------------------------------------------------
__global__ __launch_bounds__(256)
void ln_kernel(const float* base, const float* __restrict__ delta,
               const float* __restrict__ delta2,
               const float* __restrict__ g, const float* __restrict__ bb,
               float* outf, unsigned short* __restrict__ outb) {
  __shared__ float red[8];
  int row = blockIdx.x;
  int tid = threadIdx.x;
  float4 vb = ((const float4*)(base  + (size_t)row * 1024))[tid];
  float4 vd = ((const float4*)(delta + (size_t)row * 1024))[tid];
  float v0 = vb.x + vd.x, v1 = vb.y + vd.y, v2 = vb.z + vd.z, v3 = vb.w + vd.w;
  if (delta2) {
    float4 v2d = ((const float4*)(delta2 + (size_t)row * 1024))[tid];
    v0 += v2d.x; v1 += v2d.y; v2 += v2d.z; v3 += v2d.w;
  }
  float s = v0 + v1 + v2 + v3;
  float q = v0 * v0 + v1 * v1 + v2 * v2 + v3 * v3;
#pragma unroll
  for (int d = 1; d < 64; d <<= 1) { s += __shfl_xor(s, d); q += __shfl_xor(q, d); }
  int wave = tid >> 6, lane = tid & 63;
  if (lane == 0) { red[wave] = s; red[4 + wave] = q; }
  __syncthreads();
  s = red[0] + red[1] + red[2] + red[3];
  q = red[4] + red[5] + red[6] + red[7];
  float mean = s * (1.f / 1024.f);
  float var  = q * (1.f / 1024.f) - mean * mean;
  float rstd = rsqrtf(var + 1e-5f);
  float4 gg  = ((const float4*)g)[tid];
  float4 bv  = ((const float4*)bb)[tid];
  float o0 = (v0 - mean) * rstd * gg.x + bv.x;
  float o1 = (v1 - mean) * rstd * gg.y + bv.y;
  float o2 = (v2 - mean) * rstd * gg.z + bv.z;
  float o3 = (v3 - mean) * rstd * gg.w + bv.w;
  if (outf) {
    float4 o; o.x = o0; o.y = o1; o.z = o2; o.w = o3;
    ((float4*)(outf + (size_t)row * 1024))[tid] = o;
  }
  if (outb) {
    ushort4 u; u.x = f2bf(o0); u.y = f2bf(o1); u.z = f2bf(o2); u.w = f2bf(o3);
    ((ushort4*)(outb + (size_t)row * 1024))[tid] = u;
  }
}

// ---------------------------------------------------------------------------
// Launch
// ---------------------------------------------------------------------------
extern "C" void kernel_launch(void* const* d_in, const int* in_sizes, int n_in,
                              void* d_out, int out_size, void* d_ws, size_t ws_size,
                              hipStream_t stream) {
  const float* x     = (const float*)d_in[0];
  const float* y     = (const float*)d_in[1];
  const float* w_qkv = (const float*)d_in[2];
  const float* b_qkv = (const float*)d_in[3];
  const float* w_so  = (const float*)d_in[4];
  const float* b_so  = (const float*)d_in[5];
  const float* w_q   = (const float*)d_in[6];
  const float* b_q   = (const float*)d_in[7];
  const float* w_k   = (const float*)d_in[8];
  const float* b_k   = (const float*)d_in[9];
  const float* w_v   = (const float*)d_in[10];
  const float* b_v   = (const float*)d_in[11];
  const float* w_co  = (const float*)d_in[12];
  const float* b_co  = (const float*)d_in[13];
  const float* w1    = (const float*)d_in[14];
  const float* b1    = (const float*)d_in[15];
  const float* w2    = (const float*)d_in[16];
  const float* b2    = (const float*)d_in[17];
  const float* w3    = (const float*)d_in[18];
  const float* b3    = (const float*)d_in[19];
  const float* ln_g  = (const float*)d_in[20];
  const float* ln_b  = (const float*)d_in[21];

  char* ws = (char*)d_ws;
  auto US = [&](size_t off) { return (unsigned short*)(ws + off); };
  auto FP = [&](size_t off) { return (float*)(ws + off); };

  constexpr size_t o_wqkv = 0;                                 // [3072,1024] bf16
  constexpr size_t o_wso  = o_wqkv + 3072ull * 1024 * 2;       // [1024,1024]
  constexpr size_t o_wq   = o_wso  + 1024ull * 1024 * 2;
  constexpr size_t o_wk   = o_wq   + 1024ull * 1024 * 2;       // [1024,768]
  constexpr size_t o_wv   = o_wk   + 1024ull * 768 * 2;        // adjacent to wk!
  constexpr size_t o_wco  = o_wv   + 1024ull * 768 * 2;
  constexpr size_t o_w1   = o_wco  + 1024ull * 1024 * 2;       // [4096,1024]
  constexpr size_t o_w2   = o_w1   + 4096ull * 1024 * 2;       // [4096,4096]
  constexpr size_t o_w3   = o_w2   + 4096ull * 4096 * 2;       // [1024,4096]
  constexpr size_t o_xf   = o_w3   + 1024ull * 4096 * 2;       // x fp32 [4096,1024]
  constexpr size_t o_xbf  = o_xf   + 4096ull * 1024 * 4;       // x bf16
  constexpr size_t o_ybf  = o_xbf  + 4096ull * 1024 * 2;       // y bf16 [308,768]
  constexpr size_t o_dlt  = o_ybf  + 308ull * 768 * 2;         // delta fp32 [4096,1024]
  constexpr size_t o_R1   = o_dlt  + 4096ull * 1024 * 4;       // qkv bf16 [4096,3072]
  constexpr size_t o_attn = o_R1   + 4096ull * 3072 * 2;       // attn out bf16 [4096,1024]
  constexpr size_t o_R2   = o_attn + 4096ull * 1024 * 2;       // h2 bf16 [4096,4096]
  constexpr size_t o_qc  = o_R1;
  constexpr size_t o_kc  = o_R1 + 4096ull * 1024 * 2;          // merged kc|vc [308,2048]
  constexpr size_t o_h1  = o_R1;
  constexpr size_t o_h2  = o_R2;
  constexpr size_t o_dlt2 = o_R1;
  constexpr size_t o_vtS = o_R2;
  constexpr size_t o_vtC = o_R2 + 4ull * 16 * 64 * 1024 * 2;

  dim3 tb(32, 8);
  cvt_transpose<<<dim3(96, 32),  tb, 0, stream>>>(w_qkv, US(o_wqkv), 1024, 3072);
  cvt_transpose<<<dim3(32, 32),  tb, 0, stream>>>(w_so,  US(o_wso),  1024, 1024);
  cvt_transpose<<<dim3(32, 32),  tb, 0, stream>>>(w_q,   US(o_wq),   1024, 1024);
  cvt_transpose<<<dim3(32, 24),  tb, 0, stream>>>(w_k,   US(o_wk),   768,  1024);
  cvt_transpose<<<dim3(32, 24),  tb, 0, stream>>>(w_v,   US(o_wv),   768,  1024);
  cvt_transpose<<<dim3(32, 32),  tb, 0, stream>>>(w_co,  US(o_wco),  1024, 1024);
  cvt_transpose<<<dim3(128, 32), tb, 0, stream>>>(w1,    US(o_w1),   1024, 4096);
  cvt_transpose<<<dim3(128, 128),tb, 0, stream>>>(w2,    US(o_w2),   4096, 4096);
  cvt_transpose<<<dim3(32, 128), tb, 0, stream>>>(w3,    US(o_w3),   4096, 1024);

  cvt_f32_bf16<<<4096, 256, 0, stream>>>(x, US(o_xbf), 4096 * 1024 / 4);
  cvt_f32_bf16<<<231, 256, 0, stream>>>(y, US(o_ybf), 4 * 77 * 768 / 4);

  // --- self attention ---
  gemm256<false><<<dim3(12, 16), 512, 0, stream>>>(            // 8-phase + XCD swz
      US(o_xbf), US(o_wqkv), b_qkv, US(o_R1), 4096, 3072, 1024, 1024, 1024);
  transpose_v<<<dim3(16, 16, 4), 256, 0, stream>>>(
      US(o_R1) + 2048, US(o_vtS), 3072, 1024, 1024, 1024);
  attn_kernel<<<dim3(16, 16, 4), 256, 0, stream>>>(
      US(o_R1), US(o_R1) + 1024, US(o_vtS), US(o_attn),
      3072, 3072, 1024, 1024, 1024, 1024, 1024, 0.125f);
  gemm_bf16<false, true, false><<<dim3(8, 32, 2), 256, 0, stream>>>(   // split-K
      US(o_attn), US(o_wso), b_so, nullptr, 0,
      FP(o_dlt), FP(o_dlt2), nullptr, 4096, 1024, 512, 1024);
  ln_kernel<<<4096, 256, 0, stream>>>(x, FP(o_dlt), FP(o_dlt2), ln_g, ln_b,
                                      FP(o_xf), US(o_xbf));

  // --- cross attention ---
  gemm_bf16<false, false, true><<<dim3(8, 32, 1), 256, 0, stream>>>(
      US(o_xbf), US(o_wq), b_q, nullptr, 0,
      nullptr, nullptr, US(o_qc), 4096, 1024, 1024, 1024);
  // merged K|V projection: wk and wv are adjacent in ws -> one GEMM, N=2048
  gemm_bf16<false, false, true><<<dim3(16, 3, 1), 256, 0, stream>>>(
      US(o_ybf), US(o_wk), b_k, b_v, 1024,
      nullptr, nullptr, US(o_kc), 308, 2048, 768, 768);
  transpose_v<<<dim3(2, 16, 4), 256, 0, stream>>>(
      US(o_kc) + 1024, US(o_vtC), 2048, 77, 77, 128);
  attn_kernel<<<dim3(16, 16, 4), 256, 0, stream>>>(
      US(o_qc), US(o_kc), US(o_vtC), US(o_attn),
      1024, 2048, 1024, 1024, 77, 77, 128, 0.125f);
  gemm_bf16<false, true, false><<<dim3(8, 32, 2), 256, 0, stream>>>(   // split-K
      US(o_attn), US(o_wco), b_co, nullptr, 0,
      FP(o_dlt), FP(o_dlt2), nullptr, 4096, 1024, 512, 1024);
  ln_kernel<<<4096, 256, 0, stream>>>(FP(o_xf), FP(o_dlt), FP(o_dlt2), ln_g, ln_b,
                                      FP(o_xf), US(o_xbf));

  // --- FFN ---
  gemm256<true><<<dim3(16, 16), 512, 0, stream>>>(             // 8-phase + XCD swz
      US(o_xbf), US(o_w1), b1, US(o_h1), 4096, 4096, 1024, 1024, 1024);
  gemm256<true><<<dim3(16, 16), 512, 0, stream>>>(             // 8-phase + XCD swz
      US(o_h1), US(o_w2), b2, US(o_h2), 4096, 4096, 4096, 4096, 4096);
  gemm_bf16<false, true, false><<<dim3(8, 32, 2), 256, 0, stream>>>(   // split-K
      US(o_h2), US(o_w3), b3, nullptr, 0,
      FP(o_dlt), FP(o_dlt2), nullptr, 4096, 1024, 2048, 4096);
  ln_kernel<<<4096, 256, 0, stream>>>(FP(o_xf), FP(o_dlt), FP(o_dlt2), ln_g, ln_b,
                                      (float*)d_out, nullptr);
}

// Round 8
// 709.042 us; speedup vs baseline: 1.0487x; 1.0470x over previous
//
#include <hip/hip_runtime.h>
#include <hip/hip_bf16.h>
#include <math.h>

// ---------------------------------------------------------------------------
// Types
// ---------------------------------------------------------------------------
typedef short v8s __attribute__((ext_vector_type(8)));   // 8 x bf16 bits (4 VGPR)
typedef short v4s __attribute__((ext_vector_type(4)));   // 8 B
typedef float v4f __attribute__((ext_vector_type(4)));   // MFMA accumulator

__device__ __forceinline__ unsigned short f2bf(float f) {
  union { float f; unsigned u; } a; a.f = f;
  unsigned u = a.u + 0x7fffu + ((a.u >> 16) & 1u);   // RNE
  return (unsigned short)(u >> 16);
}

// async global->LDS, 16 B per lane; LDS dest = wave-uniform base + lane*16
__device__ __forceinline__ void gld_lds16(const unsigned short* g, unsigned short* l) {
  __builtin_amdgcn_global_load_lds(
      (const __attribute__((address_space(1))) void*)g,
      (__attribute__((address_space(3))) void*)l,
      16, 0, 0);
}

#define VMCNT(n)  asm volatile("s_waitcnt vmcnt(" #n ")" ::: "memory")
#define LGKM(n)   asm volatile("s_waitcnt lgkmcnt(" #n ")" ::: "memory")

// ---------------------------------------------------------------------------
// ws layout (bytes) -- file scope: shared by fused_prep and kernel_launch
// ---------------------------------------------------------------------------
constexpr size_t O_WQKV = 0;                                 // [3072,1024] bf16
constexpr size_t O_WSO  = O_WQKV + 3072ull * 1024 * 2;       // [1024,1024]
constexpr size_t O_WQ   = O_WSO  + 1024ull * 1024 * 2;
constexpr size_t O_WK   = O_WQ   + 1024ull * 1024 * 2;       // [1024,768]
constexpr size_t O_WV   = O_WK   + 1024ull * 768 * 2;        // adjacent to wk!
constexpr size_t O_WCO  = O_WV   + 1024ull * 768 * 2;
constexpr size_t O_W1   = O_WCO  + 1024ull * 1024 * 2;       // [4096,1024]
constexpr size_t O_W2   = O_W1   + 4096ull * 1024 * 2;       // [4096,4096]
constexpr size_t O_W3   = O_W2   + 4096ull * 4096 * 2;       // [1024,4096]
constexpr size_t O_XF   = O_W3   + 1024ull * 4096 * 2;       // x fp32 [4096,1024]
constexpr size_t O_XBF  = O_XF   + 4096ull * 1024 * 4;       // x bf16
constexpr size_t O_YBF  = O_XBF  + 4096ull * 1024 * 2;       // y bf16 [308,768]
constexpr size_t O_DLT  = O_YBF  + 308ull * 768 * 2;         // delta fp32 [4096,1024]
constexpr size_t O_R1   = O_DLT  + 4096ull * 1024 * 4;       // qkv bf16 [4096,3072]
constexpr size_t O_ATTN = O_R1   + 4096ull * 3072 * 2;       // attn out bf16 [4096,1024]
constexpr size_t O_R2   = O_ATTN + 4096ull * 1024 * 2;       // h2 bf16 [4096,4096]
constexpr size_t O_QC   = O_R1;
constexpr size_t O_KC   = O_R1 + 4096ull * 1024 * 2;         // merged kc|vc [308,2048]
constexpr size_t O_H1   = O_R1;
constexpr size_t O_H2   = O_R2;
constexpr size_t O_DLT2 = O_R1;
constexpr size_t O_VTS  = O_R2;
constexpr size_t O_VTC  = O_R2 + 4ull * 16 * 64 * 1024 * 2;

// ---------------------------------------------------------------------------
// fused_prep: all 9 weight transpose-converts + x/y bf16 casts in ONE launch.
// 1-D grid, compile-time block-range switch (uniform per block); each range
// replays the exact proven cvt_transpose / cvt_f32_bf16 tile code.
// Block = 256 threads (tx = tid&31, ty = tid>>5 for the transpose tiles).
// ---------------------------------------------------------------------------
__device__ __forceinline__ void cvt_tr_tile(const float* __restrict__ in,
                                            unsigned short* __restrict__ out,
                                            int K, int N, int bx, int by,
                                            float (*t)[33], int tx, int ty) {
#pragma unroll
  for (int i = 0; i < 4; i++) {
    int k = by * 32 + ty + i * 8;
    t[ty + i * 8][tx] = in[(size_t)k * N + bx * 32 + tx];
  }
  __syncthreads();
#pragma unroll
  for (int i = 0; i < 4; i++) {
    int n = bx * 32 + ty + i * 8;
    out[(size_t)n * K + by * 32 + tx] = f2bf(t[tx][ty + i * 8]);
  }
}

// block counts per range
#define NB_QKV 3072   // (96 x 32)
#define NB_SQ  1024   // (32 x 32)
#define NB_KV  768    // (32 x 24)
#define NB_W1  4096   // (128 x 32)
#define NB_W2  16384  // (128 x 128)
#define NB_W3  4096   // (32 x 128)
#define NB_X   4096   // 4096*1024/4/256
#define NB_Y   231    // 4*77*768/4/256
#define NB_PREP (NB_QKV + 5*NB_SQ - 2*(NB_SQ-NB_KV) + NB_W1 + NB_W2 + NB_W3 + NB_X + NB_Y)
// = 3072 + 1024*3 + 768*2 + 4096 + 16384 + 4096 + 4096 + 231 = 36583

__global__ __launch_bounds__(256)
void fused_prep(const float* __restrict__ x, const float* __restrict__ y,
                const float* __restrict__ w_qkv, const float* __restrict__ w_so,
                const float* __restrict__ w_q,  const float* __restrict__ w_k,
                const float* __restrict__ w_v,  const float* __restrict__ w_co,
                const float* __restrict__ w1,   const float* __restrict__ w2,
                const float* __restrict__ w3,   char* __restrict__ ws) {
  __shared__ float t[32][33];
  int tid = threadIdx.x;
  int tx = tid & 31, ty = tid >> 5;
  int bid = blockIdx.x;
  auto US = [&](size_t off) { return (unsigned short*)(ws + off); };

  if (bid < NB_QKV) { cvt_tr_tile(w_qkv, US(O_WQKV), 1024, 3072, bid % 96, bid / 96, t, tx, ty); return; }
  bid -= NB_QKV;
  if (bid < NB_SQ)  { cvt_tr_tile(w_so, US(O_WSO), 1024, 1024, bid % 32, bid / 32, t, tx, ty); return; }
  bid -= NB_SQ;
  if (bid < NB_SQ)  { cvt_tr_tile(w_q,  US(O_WQ),  1024, 1024, bid % 32, bid / 32, t, tx, ty); return; }
  bid -= NB_SQ;
  if (bid < NB_KV)  { cvt_tr_tile(w_k,  US(O_WK),  768, 1024, bid % 32, bid / 32, t, tx, ty); return; }
  bid -= NB_KV;
  if (bid < NB_KV)  { cvt_tr_tile(w_v,  US(O_WV),  768, 1024, bid % 32, bid / 32, t, tx, ty); return; }
  bid -= NB_KV;
  if (bid < NB_SQ)  { cvt_tr_tile(w_co, US(O_WCO), 1024, 1024, bid % 32, bid / 32, t, tx, ty); return; }
  bid -= NB_SQ;
  if (bid < NB_W1)  { cvt_tr_tile(w1,   US(O_W1),  1024, 4096, bid % 128, bid / 128, t, tx, ty); return; }
  bid -= NB_W1;
  if (bid < NB_W2)  { cvt_tr_tile(w2,   US(O_W2),  4096, 4096, bid % 128, bid / 128, t, tx, ty); return; }
  bid -= NB_W2;
  if (bid < NB_W3)  { cvt_tr_tile(w3,   US(O_W3),  4096, 1024, bid % 32, bid / 32, t, tx, ty); return; }
  bid -= NB_W3;
  if (bid < NB_X) {            // x fp32 -> bf16, vectorized x4
    int i = bid * 256 + tid;
    float4 v = reinterpret_cast<const float4*>(x)[i];
    ushort4 o; o.x = f2bf(v.x); o.y = f2bf(v.y); o.z = f2bf(v.z); o.w = f2bf(v.w);
    reinterpret_cast<ushort4*>(US(O_XBF))[i] = o;
    return;
  }
  bid -= NB_X;
  {                            // y fp32 -> bf16 (exactly 231*256 float4s)
    int i = bid * 256 + tid;
    float4 v = reinterpret_cast<const float4*>(y)[i];
    ushort4 o; o.x = f2bf(v.x); o.y = f2bf(v.y); o.z = f2bf(v.z); o.w = f2bf(v.w);
    reinterpret_cast<ushort4*>(US(O_YBF))[i] = o;
  }
}

// ---------------------------------------------------------------------------
// bf16 [rows, rowstride] per-head block -> Vt[b][h][64][kvpad] (V transpose)
// grid (ceil(Skv/64), H, B), 256 threads. OOB kv rows -> zero.
// ---------------------------------------------------------------------------
__global__ __launch_bounds__(256)
void transpose_v(const unsigned short* __restrict__ V,
                 unsigned short* __restrict__ Vt,
                 int rowstride, int batch_rows, int Skv, int kvpad) {
  __shared__ __align__(16) unsigned short t[64][80];
  int ch = blockIdx.x, h = blockIdx.y, b = blockIdx.z;
  int tid = threadIdx.x;
  int sr = tid >> 2, sc = (tid & 3) * 16;
  int gr = ch * 64 + sr;
  v8s v0 = {}, v1 = {};
  if (gr < Skv) {
    const unsigned short* p = V + (size_t)(b * batch_rows + gr) * rowstride + h * 64 + sc;
    v0 = *(const v8s*)p; v1 = *(const v8s*)(p + 8);
  }
  *(v8s*)&t[sr][sc]     = v0;
  *(v8s*)&t[sr][sc + 8] = v1;
  __syncthreads();
  int d  = tid >> 2;
  int k0 = (tid & 3) * 16;
  unsigned short* o = Vt + ((size_t)(b * 16 + h) * 64 + d) * kvpad + ch * 64 + k0;
  v8s o0, o1;
#pragma unroll
  for (int e = 0; e < 8; e++) { o0[e] = t[k0 + e][d]; o1[e] = t[k0 + 8 + e][d]; }
  *(v8s*)o       = o0;
  *(v8s*)(o + 8) = o1;
}

// ---------------------------------------------------------------------------
// 256x256-tile bf16 GEMM -- m201-style 8-phase template (R4 variant, the best
// measured: ~941 TF / 39% MfmaUtil / 0 bank conflicts) + T1 XCD swizzle
// (neutral dur, -6% WRITE_SIZE). Schedule variants all land 38-40% MfmaUtil
// -- declared done at this structure.
// ---------------------------------------------------------------------------
#define PH_MFMA(AFR, IB, JB)                                                   \
  _Pragma("unroll")                                                            \
  for (int m = 0; m < 4; m++) {                                                \
    _Pragma("unroll")                                                          \
    for (int n = 0; n < 2; n++) {                                              \
      acc[IB + m][JB + n] = __builtin_amdgcn_mfma_f32_16x16x32_bf16(           \
          AFR[m][0], bF[n][0], acc[IB + m][JB + n], 0, 0, 0);                  \
      acc[IB + m][JB + n] = __builtin_amdgcn_mfma_f32_16x16x32_bf16(           \
          AFR[m][1], bF[n][1], acc[IB + m][JB + n], 0, 0, 0);                  \
    }                                                                          \
  }

template<bool RELU>
__global__ __launch_bounds__(512, 2)
void gemm256(const unsigned short* __restrict__ A,
             const unsigned short* __restrict__ BT,
             const float* __restrict__ bias,
             unsigned short* __restrict__ Cb,
             int M, int N, int K, int lda, int ldb) {
  __shared__ __align__(16) unsigned short lA[2][2][8192];   // [buf][mhalf]
  __shared__ __align__(16) unsigned short lB[2][2][8192];   // [buf][nhalf]
  int tid  = threadIdx.x;
  int lane = tid & 63;
  int wave = tid >> 6;          // 0..7
  int wrow = wave >> 2;         // 0..1
  int wcol = wave & 3;          // 0..3
  int quad = lane >> 4;
  int l15  = lane & 15;

  // T1: XCD-aware swizzle (bijective; gridDim.x*gridDim.y % 8 == 0).
  int nwg  = gridDim.x * gridDim.y;
  int flat = blockIdx.y * gridDim.x + blockIdx.x;
  int q8   = nwg >> 3;
  int swz  = (flat & 7) * q8 + (flat >> 3);
  int m0 = (swz / gridDim.x) * 256;
  int n0 = (swz % gridDim.x) * 256;
  int NT = K >> 6;

  // ---- staging maps (per gld_lds call: wave w covers 8 LDS rows) ----
  int lrow = lane >> 3;                         // 0..7 row-in-wave-slice
  int swz8 = ((lane & 7) ^ lrow) << 3;          // source chunk (shorts)
  const unsigned short* gA0 = A + (size_t)(m0 + wave * 8 + lrow) * lda + swz8;
  int rr = wave * 8 + lrow;                     // 0..63
  int nbase = (rr >> 5) * 64 + (rr & 31);
  const unsigned short* gB0 = BT + (size_t)(n0 + nbase) * ldb + swz8;

  auto stageA = [&](int U, int h, int rlo) {    // 64 rows of half h
    unsigned short* d = &lA[U & 1][h][(rlo + wave * 8) * 64];
    gld_lds16(gA0 + (size_t)(h * 128 + rlo) * lda + (size_t)U * 64, d);
  };
  auto stageB = [&](int U, int hB, int q) {     // rows q*64.. of nh-half hB
    unsigned short* d = &lB[U & 1][hB][(q * 64 + wave * 8) * 64];
    gld_lds16(gB0 + (size_t)(q * 128 + hB * 32) * ldb + (size_t)U * 64, d);
  };

  // ---- ds_read swizzled chunk offsets (shorts) ----
  int ch0 = (quad ^ (l15 & 7)) << 3;            // ks=0
  int ch1 = ch0 ^ 32;                            // ks=1 (chunk^4)
  int wcol32 = wcol * 32;

  const v4f vzero = {0.f, 0.f, 0.f, 0.f};
  v4f acc[8][4];
#pragma unroll
  for (int i = 0; i < 8; i++)
#pragma unroll
    for (int j = 0; j < 4; j++) acc[i][j] = vzero;

  v8s aF0[4][2], aF1[4][2], bF[2][2];

  // ---- prologue: U1,U2,U3(0) | U4(0), U1,U2,U3(1) ----
  stageA(0, 0, 0);  stageA(0, 1, 0);      // U1(0)
  stageB(0, 0, 0);  stageB(0, 0, 1);      // U2(0)
  stageA(0, 0, 64); stageA(0, 1, 64);     // U3(0)
  stageB(0, 1, 0);  stageB(0, 1, 1);      // U4(0)
  if (NT > 1) {
    stageA(1, 0, 0);  stageA(1, 1, 0);    // U1(1)
    stageB(1, 0, 0);  stageB(1, 0, 1);    // U2(1)
    stageA(1, 0, 64); stageA(1, 1, 64);   // U3(1)
    VMCNT(8);
  } else {
    VMCNT(0);
  }
  __builtin_amdgcn_s_barrier();

  for (int U = 0; U < NT; ++U) {
    int c = U & 1;
    bool tail = (U + 3 >= NT);
    const unsigned short* pA  = &lA[c][wrow][0];
    const unsigned short* pB0 = &lB[c][0][0];
    const unsigned short* pB1 = &lB[c][1][0];

    // ===== ph0 (mh0, nh0): 12 reads =====
#pragma unroll
    for (int m = 0; m < 4; m++) {
      int ro = (m * 16 + l15) * 64;
      aF0[m][0] = *(const v8s*)&pA[ro + ch0];
      aF0[m][1] = *(const v8s*)&pA[ro + ch1];
    }
#pragma unroll
    for (int n = 0; n < 2; n++) {
      int ro = (wcol32 + n * 16 + l15) * 64;
      bF[n][0] = *(const v8s*)&pB0[ro + ch0];
      bF[n][1] = *(const v8s*)&pB0[ro + ch1];
    }
    if (U + 1 < NT) { stageB(U + 1, 1, 0); stageB(U + 1, 1, 1); }  // U4(U+1)
    LGKM(8);
    __builtin_amdgcn_s_barrier();
    LGKM(0);
    __builtin_amdgcn_sched_barrier(0);
    __builtin_amdgcn_s_setprio(1);
    PH_MFMA(aF0, 0, 0)
    __builtin_amdgcn_s_setprio(0);
    __builtin_amdgcn_s_barrier();

    // ===== ph1 (mh1, nh0): 8 reads =====
#pragma unroll
    for (int m = 0; m < 4; m++) {
      int ro = (64 * 64) + (m * 16 + l15) * 64;
      aF1[m][0] = *(const v8s*)&pA[ro + ch0];
      aF1[m][1] = *(const v8s*)&pA[ro + ch1];
    }
    if (U + 2 < NT) { stageA(U + 2, 0, 0); stageA(U + 2, 1, 0); }  // U1(U+2)
    __builtin_amdgcn_s_barrier();
    LGKM(0);
    __builtin_amdgcn_sched_barrier(0);
    __builtin_amdgcn_s_setprio(1);
    PH_MFMA(aF1, 4, 0)
    __builtin_amdgcn_s_setprio(0);
    if (tail) { VMCNT(0); } else { VMCNT(10); }    // drains U4(U) for ph2
    __builtin_amdgcn_s_barrier();

    // ===== ph2 (mh1, nh1): 4 reads =====
#pragma unroll
    for (int n = 0; n < 2; n++) {
      int ro = (wcol32 + n * 16 + l15) * 64;
      bF[n][0] = *(const v8s*)&pB1[ro + ch0];
      bF[n][1] = *(const v8s*)&pB1[ro + ch1];
    }
    if (U + 2 < NT) { stageB(U + 2, 0, 0); stageB(U + 2, 0, 1); }  // U2(U+2)
    __builtin_amdgcn_s_barrier();
    LGKM(0);
    __builtin_amdgcn_sched_barrier(0);
    __builtin_amdgcn_s_setprio(1);
    PH_MFMA(aF1, 4, 2)
    __builtin_amdgcn_s_setprio(0);
    __builtin_amdgcn_s_barrier();

    // ===== ph3 (mh0, nh1): 0 reads =====
    if (U + 2 < NT) { stageA(U + 2, 0, 64); stageA(U + 2, 1, 64); } // U3(U+2)
    __builtin_amdgcn_s_barrier();
    __builtin_amdgcn_s_setprio(1);
    PH_MFMA(aF0, 0, 2)
    __builtin_amdgcn_s_setprio(0);
    if (tail) { VMCNT(0); } else { VMCNT(8); }     // drains U1-U3(U+1)
    __builtin_amdgcn_s_barrier();
  }

  // epilogue: C/D col=lane&15, row=quad*4+reg; i=mh*4+m, j=nh*2+n
#pragma unroll
  for (int j = 0; j < 4; j++) {
    int col = n0 + wcol * 64 + (j >> 1) * 32 + (j & 1) * 16 + l15;
    float bv = bias[col];
#pragma unroll
    for (int i = 0; i < 8; i++) {
      int rb = m0 + wrow * 128 + (i >> 2) * 64 + (i & 3) * 16 + quad * 4;
#pragma unroll
      for (int r = 0; r < 4; r++) {
        int row = rb + r;
        if (row < M) {
          float v = acc[i][j][r] + bv;
          if (RELU) v = fmaxf(v, 0.f);
          Cb[(size_t)row * N + col] = f2bf(v);
        }
      }
    }
  }
}

// ---------------------------------------------------------------------------
// bf16 MFMA GEMM (128x128 2-barrier structure, proven 0 conflicts):
//   C[M,N] = act(A[M,K] @ B[K,N] + bias),  A row-major, BT=B^T [N,K].
// Kept for N=1024 GEMMs (256-tile grid would be CU-starved) and tiny M.
// bias2/bsplit: cols >= bsplit take bias2[col-bsplit] (merged-weight GEMMs).
// ---------------------------------------------------------------------------
template<bool RELU, bool OUTF, bool OUTB>
__global__ __launch_bounds__(256)
void gemm_bf16(const unsigned short* __restrict__ A,
               const unsigned short* __restrict__ BT,
               const float* __restrict__ bias,
               const float* __restrict__ bias2, int bsplit,
               float* __restrict__ Cf, float* __restrict__ Cf2,
               unsigned short* __restrict__ Cb,
               int M, int N, int Kred, int ld) {
  __shared__ __align__(16) unsigned short lA[128 * 64];   // 16 KB
  __shared__ __align__(16) unsigned short lB[128 * 64];
  int tid  = threadIdx.x;
  int lane = tid & 63;
  int wave = tid >> 6;
  int wr = (wave >> 1) * 64;
  int wc = (wave & 1) * 64;
  int quad = lane >> 4;
  int l15  = lane & 15;
  int m0 = blockIdx.y * 128;
  int n0 = blockIdx.x * 128;
  int z  = blockIdx.z;

  const unsigned short* Az = A  + (size_t)z * Kred;
  const unsigned short* Bz = BT + (size_t)z * Kred;
  float* Cfo = z ? Cf2 : Cf;
  const float* biasz = z ? nullptr : bias;

  int srow   = tid >> 3;                       // 0..31
  int schunk = (tid & 7) ^ (srow & 7);
  const unsigned short* gA = Az + (size_t)(m0 + srow) * ld + schunk * 8;
  const unsigned short* gB = Bz + (size_t)(n0 + srow) * ld + schunk * 8;
  unsigned short* ldsA = lA + wave * 512;
  unsigned short* ldsB = lB + wave * 512;
  const size_t rowblk = (size_t)32 * ld;

  const v4f vzero = {0.f, 0.f, 0.f, 0.f};
  v4f acc[4][4];
#pragma unroll
  for (int i = 0; i < 4; i++)
#pragma unroll
    for (int j = 0; j < 4; j++) acc[i][j] = vzero;

  for (int k0 = 0; k0 < Kred; k0 += 64) {
#pragma unroll
    for (int i = 0; i < 4; i++) {
      gld_lds16(gA + k0 + i * rowblk, ldsA + i * 2048);
      gld_lds16(gB + k0 + i * rowblk, ldsB + i * 2048);
    }
    __syncthreads();
#pragma unroll
    for (int s = 0; s < 2; s++) {
      v8s aF[4], bF[4];
#pragma unroll
      for (int i = 0; i < 4; i++)
        aF[i] = *(const v8s*)&lA[(wr + i * 16 + l15) * 64 + (((s * 4 + quad) ^ (l15 & 7)) * 8)];
#pragma unroll
      for (int j = 0; j < 4; j++)
        bF[j] = *(const v8s*)&lB[(wc + j * 16 + l15) * 64 + (((s * 4 + quad) ^ (l15 & 7)) * 8)];
#pragma unroll
      for (int i = 0; i < 4; i++)
#pragma unroll
        for (int j = 0; j < 4; j++)
          acc[i][j] = __builtin_amdgcn_mfma_f32_16x16x32_bf16(aF[i], bF[j], acc[i][j], 0, 0, 0);
    }
    __syncthreads();
  }

#pragma unroll
  for (int j = 0; j < 4; j++) {
    int col = n0 + wc + j * 16 + l15;
    float bv = 0.f;
    if (biasz) bv = (bias2 && col >= bsplit) ? bias2[col - bsplit] : biasz[col];
#pragma unroll
    for (int i = 0; i < 4; i++) {
#pragma unroll
      for (int r = 0; r < 4; r++) {
        int row = m0 + wr + i * 16 + quad * 4 + r;
        if (row < M) {
          float v = acc[i][j][r] + bv;
          if (RELU) v = fmaxf(v, 0.f);
          if (OUTF) Cfo[(size_t)row * N + col] = v;
          if (OUTB && !z) Cb[(size_t)row * N + col] = f2bf(v);
        }
      }
    }
  }
}

// ---------------------------------------------------------------------------
// Flash-style MFMA attention. grid (Sq/64, H, B), 256 threads = 4 waves.
// Exact R5 form (best measured). T14 async-stage split: next-chunk K/V
// global->reg prefetch issued before current chunk's compute; raw s_barrier
// + targeted lgkm waits so the prefetch survives the barrier. (R7's setprio/
// defer-max additions were net-negative in this barrier-locked 4-wave loop
// -- m190 regime, not m191 -- and are reverted.)
// ---------------------------------------------------------------------------
__global__ __launch_bounds__(256)
void attn_kernel(const unsigned short* __restrict__ Q,
                 const unsigned short* __restrict__ K,
                 const unsigned short* __restrict__ Vt,
                 unsigned short* __restrict__ O,
                 int q_rowstride, int kv_rowstride, int o_rowstride,
                 int q_batch_rows, int kv_batch_rows, int Skv, int kvpad,
                 float scale) {
  __shared__ __align__(16) unsigned short lK[64][72];      // [kv][d]
  __shared__ __align__(16) unsigned short lV[64][72];      // [d][kv]
  __shared__ __align__(16) unsigned short lP[4][16][72];   // per-wave P (A-layout src)
  int tid  = threadIdx.x;
  int lane = tid & 63;
  int wave = tid >> 6;
  int quad = lane >> 4;
  int l15  = lane & 15;
  int qt = blockIdx.x, h = blockIdx.y, b = blockIdx.z;

  const unsigned short* Qb  = Q  + (size_t)b * q_batch_rows * q_rowstride + h * 64;
  const unsigned short* Kb  = K  + (size_t)b * kv_batch_rows * kv_rowstride + h * 64;
  const unsigned short* Vtb = Vt + ((size_t)(b * 16 + h) * 64) * kvpad;

  v8s qf0, qf1;
  {
    const unsigned short* qr = Qb + (size_t)(qt * 64 + wave * 16 + l15) * q_rowstride + quad * 8;
    qf0 = *(const v8s*)(qr);
    qf1 = *(const v8s*)(qr + 32);
  }

  const v4f vzero = {0.f, 0.f, 0.f, 0.f};
  v4f o_acc[4];
#pragma unroll
  for (int t = 0; t < 4; t++) o_acc[t] = vzero;
  float m_r[4], l_r[4];
#pragma unroll
  for (int r = 0; r < 4; r++) { m_r[r] = -1e30f; l_r[r] = 0.f; }

  int sr = tid >> 2;
  int sc = (tid & 3) * 16;
  int nch = (Skv + 63) >> 6;

  // T14 prologue: prefetch chunk 0 K/V into registers
  v8s kv0 = {}, kv1 = {}, vv0, vv1;
  if (sr < Skv) {
    const unsigned short* kp = Kb + (size_t)sr * kv_rowstride + sc;
    kv0 = *(const v8s*)kp;  kv1 = *(const v8s*)(kp + 8);
  }
  {
    const unsigned short* vp = Vtb + (size_t)sr * kvpad + sc;
    vv0 = *(const v8s*)vp;  vv1 = *(const v8s*)(vp + 8);
  }

  for (int ch = 0; ch < nch; ch++) {
    int base = ch * 64;
    __builtin_amdgcn_s_barrier();           // prev chunk's LDS reads consumed
    __builtin_amdgcn_sched_barrier(0);
    *(v8s*)&lK[sr][sc]     = kv0;
    *(v8s*)&lK[sr][sc + 8] = kv1;
    {  // lV row stride 72 shorts: 16B-unaligned for odd rows -> 8B stores
      v4s a0 = {vv0[0], vv0[1], vv0[2], vv0[3]};
      v4s a1 = {vv0[4], vv0[5], vv0[6], vv0[7]};
      v4s a2 = {vv1[0], vv1[1], vv1[2], vv1[3]};
      v4s a3 = {vv1[4], vv1[5], vv1[6], vv1[7]};
      *(v4s*)&lV[sr][sc]      = a0;
      *(v4s*)&lV[sr][sc + 4]  = a1;
      *(v4s*)&lV[sr][sc + 8]  = a2;
      *(v4s*)&lV[sr][sc + 12] = a3;
    }
    // issue next-chunk loads (latency hides under the compute below)
    v8s kn0 = {}, kn1 = {}, vn0 = {}, vn1 = {};
    if (ch + 1 < nch) {
      int gr2 = base + 64 + sr;
      if (gr2 < Skv) {
        const unsigned short* kp2 = Kb + (size_t)gr2 * kv_rowstride + sc;
        kn0 = *(const v8s*)kp2;  kn1 = *(const v8s*)(kp2 + 8);
      }
      const unsigned short* vp2 = Vtb + (size_t)sr * kvpad + base + 64 + sc;
      vn0 = *(const v8s*)vp2;  vn1 = *(const v8s*)(vp2 + 8);
    }
    LGKM(0);                                 // own ds_writes landed
    __builtin_amdgcn_s_barrier();            // all writes visible
    __builtin_amdgcn_sched_barrier(0);

    float s[4][4];
#pragma unroll
    for (int t = 0; t < 4; t++) {
      v8s kf0 = *(const v8s*)&lK[t * 16 + l15][quad * 8];
      v8s kf1 = *(const v8s*)&lK[t * 16 + l15][32 + quad * 8];
      v4f sacc = vzero;
      sacc = __builtin_amdgcn_mfma_f32_16x16x32_bf16(qf0, kf0, sacc, 0, 0, 0);
      sacc = __builtin_amdgcn_mfma_f32_16x16x32_bf16(qf1, kf1, sacc, 0, 0, 0);
      int kvpos = base + t * 16 + l15;
      bool ok = kvpos < Skv;
#pragma unroll
      for (int r = 0; r < 4; r++) s[t][r] = ok ? sacc[r] * scale : -1e30f;
    }

#pragma unroll
    for (int r = 0; r < 4; r++) {
      float mx = fmaxf(fmaxf(s[0][r], s[1][r]), fmaxf(s[2][r], s[3][r]));
#pragma unroll
      for (int d = 1; d < 16; d <<= 1) mx = fmaxf(mx, __shfl_xor(mx, d));
      float mnew = fmaxf(m_r[r], mx);
      float alpha = __expf(m_r[r] - mnew);
      float sm = 0.f;
#pragma unroll
      for (int t = 0; t < 4; t++) { s[t][r] = __expf(s[t][r] - mnew); sm += s[t][r]; }
#pragma unroll
      for (int d = 1; d < 16; d <<= 1) sm += __shfl_xor(sm, d);
      l_r[r] = l_r[r] * alpha + sm;
      m_r[r] = mnew;
#pragma unroll
      for (int t = 0; t < 4; t++) o_acc[t][r] *= alpha;
    }

#pragma unroll
    for (int t = 0; t < 4; t++)
#pragma unroll
      for (int r = 0; r < 4; r++)
        lP[wave][quad * 4 + r][t * 16 + l15] = f2bf(s[t][r]);
    v8s pf0 = *(const v8s*)&lP[wave][l15][quad * 8];
    v8s pf1 = *(const v8s*)&lP[wave][l15][32 + quad * 8];
#pragma unroll
    for (int t = 0; t < 4; t++) {
      v8s vf0 = *(const v8s*)&lV[t * 16 + l15][quad * 8];
      v8s vf1 = *(const v8s*)&lV[t * 16 + l15][32 + quad * 8];
      o_acc[t] = __builtin_amdgcn_mfma_f32_16x16x32_bf16(pf0, vf0, o_acc[t], 0, 0, 0);
      o_acc[t] = __builtin_amdgcn_mfma_f32_16x16x32_bf16(pf1, vf1, o_acc[t], 0, 0, 0);
    }

    kv0 = kn0; kv1 = kn1; vv0 = vn0; vv1 = vn1;
  }

  int orow0 = b * q_batch_rows + qt * 64 + wave * 16;
#pragma unroll
  for (int t = 0; t < 4; t++) {
#pragma unroll
    for (int r = 0; r < 4; r++) {
      float v = o_acc[t][r] / l_r[r];
      O[(size_t)(orow0 + quad * 4 + r) * o_rowstride + h * 64 + t * 16 + l15] = f2bf(v);
    }
  }
}

// ---------------------------------------------------------------------------
// Fused residual + LayerNorm over D=1024. 256 threads, 4 cols/thread.
// ---------------------------------------------------------------------------
__global__ __launch_bounds__(256)
void ln_kernel(const float* base, const float* __restrict__ delta,
               const float* __restrict__ delta2,
               const float* __restrict__ g, const float* __restrict__ bb,
               float* outf, unsigned short* __restrict__ outb) {
  __shared__ float red[8];
  int row = blockIdx.x;
  int tid = threadIdx.x;
  float4 vb = ((const float4*)(base  + (size_t)row * 1024))[tid];
  float4 vd = ((const float4*)(delta + (size_t)row * 1024))[tid];
  float v0 = vb.x + vd.x, v1 = vb.y + vd.y, v2 = vb.z + vd.z, v3 = vb.w + vd.w;
  if (delta2) {
    float4 v2d = ((const float4*)(delta2 + (size_t)row * 1024))[tid];
    v0 += v2d.x; v1 += v2d.y; v2 += v2d.z; v3 += v2d.w;
  }
  float s = v0 + v1 + v2 + v3;
  float q = v0 * v0 + v1 * v1 + v2 * v2 + v3 * v3;
#pragma unroll
  for (int d = 1; d < 64; d <<= 1) { s += __shfl_xor(s, d); q += __shfl_xor(q, d); }
  int wave = tid >> 6, lane = tid & 63;
  if (lane == 0) { red[wave] = s; red[4 + wave] = q; }
  __syncthreads();
  s = red[0] + red[1] + red[2] + red[3];
  q = red[4] + red[5] + red[6] + red[7];
  float mean = s * (1.f / 1024.f);
  float var  = q * (1.f / 1024.f) - mean * mean;
  float rstd = rsqrtf(var + 1e-5f);
  float4 gg  = ((const float4*)g)[tid];
  float4 bv  = ((const float4*)bb)[tid];
  float o0 = (v0 - mean) * rstd * gg.x + bv.x;
  float o1 = (v1 - mean) * rstd * gg.y + bv.y;
  float o2 = (v2 - mean) * rstd * gg.z + bv.z;
  float o3 = (v3 - mean) * rstd * gg.w + bv.w;
  if (outf) {
    float4 o; o.x = o0; o.y = o1; o.z = o2; o.w = o3;
    ((float4*)(outf + (size_t)row * 1024))[tid] = o;
  }
  if (outb) {
    ushort4 u; u.x = f2bf(o0); u.y = f2bf(o1); u.z = f2bf(o2); u.w = f2bf(o3);
    ((ushort4*)(outb + (size_t)row * 1024))[tid] = u;
  }
}

// ---------------------------------------------------------------------------
// Launch
// ---------------------------------------------------------------------------
extern "C" void kernel_launch(void* const* d_in, const int* in_sizes, int n_in,
                              void* d_out, int out_size, void* d_ws, size_t ws_size,
                              hipStream_t stream) {
  const float* x     = (const float*)d_in[0];
  const float* y     = (const float*)d_in[1];
  const float* w_qkv = (const float*)d_in[2];
  const float* b_qkv = (const float*)d_in[3];
  const float* w_so  = (const float*)d_in[4];
  const float* b_so  = (const float*)d_in[5];
  const float* w_q   = (const float*)d_in[6];
  const float* b_q   = (const float*)d_in[7];
  const float* w_k   = (const float*)d_in[8];
  const float* b_k   = (const float*)d_in[9];
  const float* w_v   = (const float*)d_in[10];
  const float* b_v   = (const float*)d_in[11];
  const float* w_co  = (const float*)d_in[12];
  const float* b_co  = (const float*)d_in[13];
  const float* w1    = (const float*)d_in[14];
  const float* b1    = (const float*)d_in[15];
  const float* w2    = (const float*)d_in[16];
  const float* b2    = (const float*)d_in[17];
  const float* w3    = (const float*)d_in[18];
  const float* b3    = (const float*)d_in[19];
  const float* ln_g  = (const float*)d_in[20];
  const float* ln_b  = (const float*)d_in[21];

  char* ws = (char*)d_ws;
  auto US = [&](size_t off) { return (unsigned short*)(ws + off); };
  auto FP = [&](size_t off) { return (float*)(ws + off); };

  // --- fused prep: 9 weight transpose-converts + x/y casts in ONE launch ---
  fused_prep<<<36583, 256, 0, stream>>>(x, y, w_qkv, w_so, w_q, w_k, w_v,
                                        w_co, w1, w2, w3, ws);

  // --- self attention ---
  gemm256<false><<<dim3(12, 16), 512, 0, stream>>>(            // 8-phase + XCD swz
      US(O_XBF), US(O_WQKV), b_qkv, US(O_R1), 4096, 3072, 1024, 1024, 1024);
  transpose_v<<<dim3(16, 16, 4), 256, 0, stream>>>(
      US(O_R1) + 2048, US(O_VTS), 3072, 1024, 1024, 1024);
  attn_kernel<<<dim3(16, 16, 4), 256, 0, stream>>>(
      US(O_R1), US(O_R1) + 1024, US(O_VTS), US(O_ATTN),
      3072, 3072, 1024, 1024, 1024, 1024, 1024, 0.125f);
  gemm_bf16<false, true, false><<<dim3(8, 32, 2), 256, 0, stream>>>(   // split-K
      US(O_ATTN), US(O_WSO), b_so, nullptr, 0,
      FP(O_DLT), FP(O_DLT2), nullptr, 4096, 1024, 512, 1024);
  ln_kernel<<<4096, 256, 0, stream>>>(x, FP(O_DLT), FP(O_DLT2), ln_g, ln_b,
                                      FP(O_XF), US(O_XBF));

  // --- cross attention ---
  gemm_bf16<false, false, true><<<dim3(8, 32, 1), 256, 0, stream>>>(
      US(O_XBF), US(O_WQ), b_q, nullptr, 0,
      nullptr, nullptr, US(O_QC), 4096, 1024, 1024, 1024);
  // merged K|V projection: wk and wv are adjacent in ws -> one GEMM, N=2048
  gemm_bf16<false, false, true><<<dim3(16, 3, 1), 256, 0, stream>>>(
      US(O_YBF), US(O_WK), b_k, b_v, 1024,
      nullptr, nullptr, US(O_KC), 308, 2048, 768, 768);
  transpose_v<<<dim3(2, 16, 4), 256, 0, stream>>>(
      US(O_KC) + 1024, US(O_VTC), 2048, 77, 77, 128);
  attn_kernel<<<dim3(16, 16, 4), 256, 0, stream>>>(
      US(O_QC), US(O_KC), US(O_VTC), US(O_ATTN),
      1024, 2048, 1024, 1024, 77, 77, 128, 0.125f);
  gemm_bf16<false, true, false><<<dim3(8, 32, 2), 256, 0, stream>>>(   // split-K
      US(O_ATTN), US(O_WCO), b_co, nullptr, 0,
      FP(O_DLT), FP(O_DLT2), nullptr, 4096, 1024, 512, 1024);
  ln_kernel<<<4096, 256, 0, stream>>>(FP(O_XF), FP(O_DLT), FP(O_DLT2), ln_g, ln_b,
                                      FP(O_XF), US(O_XBF));

  // --- FFN ---
  gemm256<true><<<dim3(16, 16), 512, 0, stream>>>(             // 8-phase + XCD swz
      US(O_XBF), US(O_W1), b1, US(O_H1), 4096, 4096, 1024, 1024, 1024);
  gemm256<true><<<dim3(16, 16), 512, 0, stream>>>(             // 8-phase + XCD swz
      US(O_H1), US(O_W2), b2, US(O_H2), 4096, 4096, 4096, 4096, 4096);
  gemm_bf16<false, true, false><<<dim3(8, 32, 2), 256, 0, stream>>>(   // split-K
      US(O_H2), US(O_W3), b3, nullptr, 0,
      FP(O_DLT), FP(O_DLT2), nullptr, 4096, 1024, 2048, 4096);
  ln_kernel<<<4096, 256, 0, stream>>>(FP(O_XF), FP(O_DLT), FP(O_DLT2), ln_g, ln_b,
                                      (float*)d_out, nullptr);
}